// Round 7
// baseline (484.735 us; speedup 1.0000x reference)
//
#include <hip/hip_runtime.h>

// GraphSAGE forward, decoupled: pure CSR gather kernel (wave-per-node, no barriers)
// + per-tile MFMA matmul kernel (1 wave / 16-node tile, bf16x3 split).
#define N_NODES 50000
#define N_EDGES 800000
#define D 64
#define N_GRAPHS 512
#define D_TARGET 10
#define NB_SCAN ((N_NODES + 255) / 256)   // 196
#define TPAD 72                            // LDS tile row stride in bf16 (36 dwords -> 2-way max)

typedef __attribute__((ext_vector_type(8))) short short8;
typedef __attribute__((ext_vector_type(4))) float f32x4;
#define MFMA16(a, b, c) __builtin_amdgcn_mfma_f32_16x16x32_bf16(a, b, c, 0, 0, 0)

__device__ inline unsigned short bf16rne(float f) {
    unsigned u = __builtin_bit_cast(unsigned, f);
    u += 0x7FFFu + ((u >> 16) & 1u);
    return (unsigned short)(u >> 16);
}
__device__ inline float bf2f(unsigned short h) {
    unsigned u = ((unsigned)h) << 16;
    return __builtin_bit_cast(float, u);
}

// ---- int degree histogram + float graph-count ----
__global__ void count_kernel(const int* __restrict__ dst, const int* __restrict__ batch,
                             int* __restrict__ degi, float* __restrict__ gcnt) {
    int i = blockIdx.x * blockDim.x + threadIdx.x;
    if (i < N_EDGES) atomicAdd(&degi[dst[i]], 1);
    if (i < N_NODES) atomicAdd(&gcnt[batch[i]], 1.0f);
}

__global__ void scan_partials(const int* __restrict__ degi, int* __restrict__ partial) {
    __shared__ int s[256];
    int t = threadIdx.x;
    int i = blockIdx.x * 256 + t;
    s[t] = (i < N_NODES) ? degi[i] : 0;
    __syncthreads();
    for (int off = 128; off > 0; off >>= 1) {
        if (t < off) s[t] += s[t + off];
        __syncthreads();
    }
    if (t == 0) partial[blockIdx.x] = s[0];
}

__global__ void scan_offsets(int* __restrict__ partial) {
    if (threadIdx.x == 0) {
        int run = 0;
        for (int i = 0; i < NB_SCAN; ++i) { int p = partial[i]; partial[i] = run; run += p; }
    }
}

__global__ void scan_final(const int* __restrict__ degi, const int* __restrict__ partial,
                           int* __restrict__ rowptr, int* __restrict__ next) {
    __shared__ int s[256];
    int t = threadIdx.x;
    int i = blockIdx.x * 256 + t;
    int v = (i < N_NODES) ? degi[i] : 0;
    s[t] = v;
    __syncthreads();
    for (int off = 1; off < 256; off <<= 1) {
        int add = (t >= off) ? s[t - off] : 0;
        __syncthreads();
        s[t] += add;
        __syncthreads();
    }
    if (i < N_NODES) {
        int excl = partial[blockIdx.x] + s[t] - v;
        rowptr[i] = excl;
        next[i]   = excl;
    }
    if (i == 0) rowptr[N_NODES] = N_EDGES;
}

__global__ void fill_kernel(const int* __restrict__ src, const int* __restrict__ dst,
                            int* __restrict__ next, int* __restrict__ col) {
    int e = blockIdx.x * blockDim.x + threadIdx.x;
    if (e < N_EDGES) {
        int pos = atomicAdd(&next[dst[e]], 1);
        col[pos] = src[e];
    }
}

// ---- weight prep: fp32 [64][64] -> bf16 hi/lo in MFMA B-fragment order ----
__global__ void wprep_kernel(const float* __restrict__ w0, const float* __restrict__ w1,
                             const float* __restrict__ w2, const float* __restrict__ w3,
                             const float* __restrict__ w4, const float* __restrict__ w5,
                             const float* __restrict__ w6, short* __restrict__ out) {
    int tid = blockIdx.x * 256 + threadIdx.x;   // 0 .. 7*4096-1
    int m = tid >> 12, t = tid & 4095;
    const float* W = (m == 0) ? w0 : (m == 1) ? w1 : (m == 2) ? w2 : (m == 3) ? w3
                   : (m == 4) ? w4 : (m == 5) ? w5 : w6;
    int j = t & 7, lane = (t >> 3) & 63, nt = (t >> 9) & 3, kt = t >> 11;
    int k = kt * 32 + ((lane >> 4) << 3) + j;
    int o = nt * 16 + (lane & 15);
    float v = W[k * 64 + o];
    unsigned short hi = bf16rne(v);
    unsigned short lo = bf16rne(v - bf2f(hi));
    out[m * 8192 + t]        = (short)hi;
    out[m * 8192 + 4096 + t] = (short)lo;
}

// ---- pure gather: one wave per node, no LDS, no barriers; writes mean row fp32 ----
__global__ __launch_bounds__(512) void gather_kernel(
    const float* __restrict__ h_in, const int* __restrict__ rowptr,
    const int* __restrict__ col, float* __restrict__ meanout) {
    int gw   = (blockIdx.x * 512 + threadIdx.x) >> 6;   // global wave id = node
    int lane = threadIdx.x & 63;
    int f = lane & 15;    // float4 chunk
    int g = lane >> 4;    // subgroup 0..3
    if (gw >= N_NODES) return;
    int beg = rowptr[gw], end = rowptr[gw + 1];
    const float4* h4 = (const float4*)h_in;

    float4 a0 = make_float4(0.f, 0.f, 0.f, 0.f);
    float4 a1 = a0, a2 = a0, a3 = a0;
    int p = beg + g;
    for (; p + 12 < end; p += 16) {
        int s0 = col[p], s1 = col[p + 4], s2 = col[p + 8], s3 = col[p + 12];
        float4 v0 = h4[s0 * 16 + f];
        float4 v1 = h4[s1 * 16 + f];
        float4 v2 = h4[s2 * 16 + f];
        float4 v3 = h4[s3 * 16 + f];
        a0.x += v0.x; a0.y += v0.y; a0.z += v0.z; a0.w += v0.w;
        a1.x += v1.x; a1.y += v1.y; a1.z += v1.z; a1.w += v1.w;
        a2.x += v2.x; a2.y += v2.y; a2.z += v2.z; a2.w += v2.w;
        a3.x += v3.x; a3.y += v3.y; a3.z += v3.z; a3.w += v3.w;
    }
    for (; p < end; p += 4) {
        float4 v = h4[col[p] * 16 + f];
        a0.x += v.x; a0.y += v.y; a0.z += v.z; a0.w += v.w;
    }
    a0.x += a1.x + a2.x + a3.x;
    a0.y += a1.y + a2.y + a3.y;
    a0.z += a1.z + a2.z + a3.z;
    a0.w += a1.w + a2.w + a3.w;
    a0.x += __shfl_xor(a0.x, 16); a0.y += __shfl_xor(a0.y, 16);
    a0.z += __shfl_xor(a0.z, 16); a0.w += __shfl_xor(a0.w, 16);
    a0.x += __shfl_xor(a0.x, 32); a0.y += __shfl_xor(a0.y, 32);
    a0.z += __shfl_xor(a0.z, 32); a0.w += __shfl_xor(a0.w, 32);
    if (g == 0) {
        float inv = 1.0f / fmaxf((float)(end - beg), 1.0f);
        ((float4*)meanout)[gw * 16 + f] =
            make_float4(a0.x * inv, a0.y * inv, a0.z * inv, a0.w * inv);
    }
}

// ---- per-tile matmul: one wave handles 16 nodes; wave-local LDS, no barriers ----
// stage mean+x (fp32, sequential) -> bf16 hi/lo tiles; mat1 -> t tiles; mat2 -> out.
__global__ __launch_bounds__(64) void mm_kernel(
    const float* __restrict__ h_in, const float* __restrict__ meanin,
    const short* __restrict__ wl, const short* __restrict__ wr, const short* __restrict__ wm,
    const float* __restrict__ blv, const float* __restrict__ bmv,
    const int* __restrict__ batch,
    float* __restrict__ h_out, float* __restrict__ gsum, int col_off) {
    __shared__ short smh[16 * TPAD];
    __shared__ short sml[16 * TPAD];
    __shared__ short sxh[16 * TPAD];
    __shared__ short sxl[16 * TPAD];
    __shared__ short sth[16 * TPAD];
    __shared__ short stl[16 * TPAD];

    int lane = threadIdx.x;
    int f = lane & 15;
    int g = lane >> 4;
    int base = blockIdx.x * 16;
    const float4* h4 = (const float4*)h_in;
    const float4* m4 = (const float4*)meanin;

    // stage 16 rows x 16 float4 for mean and x; coalesced (idx = i*64 + lane)
#pragma unroll
    for (int i = 0; i < 4; ++i) {
        int idx = i * 64 + lane;
        int r = idx >> 4, c = idx & 15;
        float4 mv = m4[(base + r) * 16 + c];
        float4 xv = h4[(base + r) * 16 + c];
        unsigned short mh0 = bf16rne(mv.x), mh1 = bf16rne(mv.y), mh2 = bf16rne(mv.z), mh3 = bf16rne(mv.w);
        unsigned short xh0 = bf16rne(xv.x), xh1 = bf16rne(xv.y), xh2 = bf16rne(xv.z), xh3 = bf16rne(xv.w);
        uint2 hw, lw;
        hw.x = (unsigned)mh0 | ((unsigned)mh1 << 16);
        hw.y = (unsigned)mh2 | ((unsigned)mh3 << 16);
        lw.x = (unsigned)bf16rne(mv.x - bf2f(mh0)) | ((unsigned)bf16rne(mv.y - bf2f(mh1)) << 16);
        lw.y = (unsigned)bf16rne(mv.z - bf2f(mh2)) | ((unsigned)bf16rne(mv.w - bf2f(mh3)) << 16);
        *(uint2*)&smh[r * TPAD + c * 4] = hw;
        *(uint2*)&sml[r * TPAD + c * 4] = lw;
        hw.x = (unsigned)xh0 | ((unsigned)xh1 << 16);
        hw.y = (unsigned)xh2 | ((unsigned)xh3 << 16);
        lw.x = (unsigned)bf16rne(xv.x - bf2f(xh0)) | ((unsigned)bf16rne(xv.y - bf2f(xh1)) << 16);
        lw.y = (unsigned)bf16rne(xv.z - bf2f(xh2)) | ((unsigned)bf16rne(xv.w - bf2f(xh3)) << 16);
        *(uint2*)&sxh[r * TPAD + c * 4] = hw;
        *(uint2*)&sxl[r * TPAD + c * 4] = lw;
    }
    // wave-local LDS: compiler inserts lgkmcnt waits; no barrier needed.

    // A-fragments: lane holds row f, k-chunk g*8 + kt*32
    short8 amh[2], aml[2], axh[2], axl[2];
#pragma unroll
    for (int kt = 0; kt < 2; ++kt) {
        int idx = f * TPAD + kt * 32 + g * 8;
        amh[kt] = *(const short8*)&smh[idx];
        aml[kt] = *(const short8*)&sml[idx];
        axh[kt] = *(const short8*)&sxh[idx];
        axl[kt] = *(const short8*)&sxl[idx];
    }
    const short* wlh = wl;
    const short* wll = wl + 4096;
    const short* wrh = wr;
    const short* wrl = wr + 4096;

    // ---- mat1: t = mean@Wl + bl + x@Wr ----
#pragma unroll
    for (int nt = 0; nt < 4; ++nt) {
        f32x4 acc = {0.f, 0.f, 0.f, 0.f};
#pragma unroll
        for (int kt = 0; kt < 2; ++kt) {
            int fi = ((kt * 4 + nt) * 64 + lane) * 8;
            short8 blh = *(const short8*)&wlh[fi];
            short8 bll = *(const short8*)&wll[fi];
            short8 brh = *(const short8*)&wrh[fi];
            short8 brl = *(const short8*)&wrl[fi];
            acc = MFMA16(amh[kt], blh, acc);
            acc = MFMA16(aml[kt], blh, acc);
            acc = MFMA16(amh[kt], bll, acc);
            acc = MFMA16(axh[kt], brh, acc);
            acc = MFMA16(axl[kt], brh, acc);
            acc = MFMA16(axh[kt], brl, acc);
        }
        float bias = blv[nt * 16 + f];
#pragma unroll
        for (int r = 0; r < 4; ++r) {
            float tv = acc[r] + bias;
            unsigned short hi = bf16rne(tv);
            unsigned short lo = bf16rne(tv - bf2f(hi));
            int row = g * 4 + r;   // C layout: row=(lane>>4)*4+r, col=lane&15
            sth[row * TPAD + nt * 16 + f] = (short)hi;
            stl[row * TPAD + nt * 16 + f] = (short)lo;
        }
    }

    // ---- mat2: h = relu(t@Wm + bm) ----
    short8 ath[2], atl[2];
#pragma unroll
    for (int kt = 0; kt < 2; ++kt) {
        int idx = f * TPAD + kt * 32 + g * 8;
        ath[kt] = *(const short8*)&sth[idx];
        atl[kt] = *(const short8*)&stl[idx];
    }
    const short* wmh = wm;
    const short* wml = wm + 4096;
#pragma unroll
    for (int nt = 0; nt < 4; ++nt) {
        f32x4 acc = {0.f, 0.f, 0.f, 0.f};
#pragma unroll
        for (int kt = 0; kt < 2; ++kt) {
            int fi = ((kt * 4 + nt) * 64 + lane) * 8;
            short8 bh  = *(const short8*)&wmh[fi];
            short8 bl2 = *(const short8*)&wml[fi];
            acc = MFMA16(ath[kt], bh, acc);
            acc = MFMA16(atl[kt], bh, acc);
            acc = MFMA16(ath[kt], bl2, acc);
        }
        float bias = bmv[nt * 16 + f];
#pragma unroll
        for (int r = 0; r < 4; ++r) {
            float hv = acc[r] + bias;
            hv = hv > 0.f ? hv : 0.f;
            int row  = g * 4 + r;
            int node = base + row;
            h_out[node * D + nt * 16 + f] = hv;
            atomicAdd(&gsum[batch[node] * (3 * D) + col_off + nt * 16 + f], hv);
        }
    }
}

// ---- pooled MLP: g = gsum/cnt; t = relu(g@W1+b1); out = t@W2+b2 ----
__global__ void pool_mlp_kernel(const float* __restrict__ gsum, const float* __restrict__ gcnt,
                                const float* __restrict__ W1, const float* __restrict__ b1,
                                const float* __restrict__ W2, const float* __restrict__ b2,
                                float* __restrict__ out) {
    __shared__ float g[3 * D];
    __shared__ float tt[D];
    int gr = blockIdx.x;
    int t  = threadIdx.x;  // 64 threads
    float cnt = gcnt[gr];
    if (cnt < 1.f) cnt = 1.f;
    for (int i = t; i < 3 * D; i += 64) g[i] = gsum[gr * 3 * D + i] / cnt;
    __syncthreads();

    float acc = b1[t];
#pragma unroll 8
    for (int k = 0; k < 3 * D; ++k) acc += g[k] * W1[k * D + t];
    tt[t] = acc > 0.f ? acc : 0.f;
    __syncthreads();

    if (t < D_TARGET) {
        float acc2 = b2[t];
#pragma unroll
        for (int k = 0; k < D; ++k) acc2 += tt[k] * W2[k * D_TARGET + t];
        out[gr * D_TARGET + t] = acc2;
    }
}

extern "C" void kernel_launch(void* const* d_in, const int* in_sizes, int n_in,
                              void* d_out, int out_size, void* d_ws, size_t ws_size,
                              hipStream_t stream) {
    const float* x     = (const float*)d_in[0];
    const int*   ei    = (const int*)d_in[1];
    const int*   src   = ei;
    const int*   dst   = ei + N_EDGES;
    const int*   batch = (const int*)d_in[2];

    const float* Wl[3] = {(const float*)d_in[3], (const float*)d_in[6], (const float*)d_in[9]};
    const float* bl[3] = {(const float*)d_in[4], (const float*)d_in[7], (const float*)d_in[10]};
    const float* Wr[3] = {(const float*)d_in[5], (const float*)d_in[8], (const float*)d_in[11]};
    const float* Wm = (const float*)d_in[12];
    const float* bm = (const float*)d_in[13];
    const float* W1 = (const float*)d_in[14];
    const float* b1 = (const float*)d_in[15];
    const float* W2 = (const float*)d_in[16];
    const float* b2 = (const float*)d_in[17];

    // workspace layout (4-byte words)
    int*   degi    = (int*)d_ws;                       // 50000
    float* gsum    = (float*)(degi + N_NODES);         // 98304
    float* gcnt    = gsum + N_GRAPHS * 3 * D;          // 512
    int*   partial = (int*)(gcnt + N_GRAPHS);          // 256
    int*   rowptr  = partial + 256;                    // 50001
    int*   next    = rowptr + N_NODES + 1;             // 50000
    int*   col     = next + N_NODES;                   // 800000
    short* wfrag   = (short*)(col + N_EDGES + 3);      // 16B aligned; 7*8192 shorts
    float* hA      = (float*)(wfrag + 7 * 8192);       // 3,200,000
    float* hB      = hA + (size_t)N_NODES * D;         // 3,200,000
    float* meanb   = hB + (size_t)N_NODES * D;         // 3,200,000  (~42.5 MB total)

    // zero degi + gsum + gcnt (contiguous)
    hipMemsetAsync(degi, 0, (N_NODES + N_GRAPHS * 3 * D + N_GRAPHS) * sizeof(float), stream);

    count_kernel<<<(N_EDGES + 255) / 256, 256, 0, stream>>>(dst, batch, degi, gcnt);
    scan_partials<<<NB_SCAN, 256, 0, stream>>>(degi, partial);
    scan_offsets<<<1, 64, 0, stream>>>(partial);
    scan_final<<<NB_SCAN, 256, 0, stream>>>(degi, partial, rowptr, next);
    fill_kernel<<<(N_EDGES + 255) / 256, 256, 0, stream>>>(src, dst, next, col);
    wprep_kernel<<<7 * 4096 / 256, 256, 0, stream>>>(
        Wl[0], Wr[0], Wl[1], Wr[1], Wl[2], Wr[2], Wm, wfrag);

    const float* hin = x;
    float* hout = hA;
    for (int l = 0; l < 3; ++l) {
        gather_kernel<<<(N_NODES * 64 + 511) / 512, 512, 0, stream>>>(hin, rowptr, col, meanb);
        mm_kernel<<<N_NODES / 16, 64, 0, stream>>>(
            hin, meanb,
            wfrag + (2 * l) * 8192, wfrag + (2 * l + 1) * 8192, wfrag + 6 * 8192,
            bl[l], bm, batch, hout, gsum, l * D);
        hin  = hout;
        hout = (hout == hA) ? hB : hA;
    }

    pool_mlp_kernel<<<N_GRAPHS, 64, 0, stream>>>(gsum, gcnt, W1, b1, W2, b2, (float*)d_out);
}

// Round 9
// 261.615 us; speedup vs baseline: 1.8529x; 1.8529x over previous
//
#include <hip/hip_runtime.h>

// GraphSAGE forward, atomic-free pooling: CSR gather + MFMA matmul (bf16x3) +
// segmented mean-pool over sorted batch + fused MLP.
#define N_NODES 50000
#define N_EDGES 800000
#define D 64
#define N_GRAPHS 512
#define D_TARGET 10
#define NB_SCAN ((N_NODES + 255) / 256)   // 196
#define TPAD 72                            // LDS tile row stride in bf16

typedef __attribute__((ext_vector_type(8))) short short8;
typedef __attribute__((ext_vector_type(4))) float f32x4;
#define MFMA16(a, b, c) __builtin_amdgcn_mfma_f32_16x16x32_bf16(a, b, c, 0, 0, 0)

__device__ inline unsigned short bf16rne(float f) {
    unsigned u = __builtin_bit_cast(unsigned, f);
    u += 0x7FFFu + ((u >> 16) & 1u);
    return (unsigned short)(u >> 16);
}
__device__ inline float bf2f(unsigned short h) {
    unsigned u = ((unsigned)h) << 16;
    return __builtin_bit_cast(float, u);
}

// ---- int degree histogram ----
__global__ void count_kernel(const int* __restrict__ dst, int* __restrict__ degi) {
    int i = blockIdx.x * blockDim.x + threadIdx.x;
    if (i < N_EDGES) atomicAdd(&degi[dst[i]], 1);
}

__global__ void scan_partials(const int* __restrict__ degi, int* __restrict__ partial) {
    __shared__ int s[256];
    int t = threadIdx.x;
    int i = blockIdx.x * 256 + t;
    s[t] = (i < N_NODES) ? degi[i] : 0;
    __syncthreads();
    for (int off = 128; off > 0; off >>= 1) {
        if (t < off) s[t] += s[t + off];
        __syncthreads();
    }
    if (t == 0) partial[blockIdx.x] = s[0];
}

__global__ void scan_offsets(int* __restrict__ partial) {
    if (threadIdx.x == 0) {
        int run = 0;
        for (int i = 0; i < NB_SCAN; ++i) { int p = partial[i]; partial[i] = run; run += p; }
    }
}

__global__ void scan_final(const int* __restrict__ degi, const int* __restrict__ partial,
                           int* __restrict__ rowptr, int* __restrict__ next) {
    __shared__ int s[256];
    int t = threadIdx.x;
    int i = blockIdx.x * 256 + t;
    int v = (i < N_NODES) ? degi[i] : 0;
    s[t] = v;
    __syncthreads();
    for (int off = 1; off < 256; off <<= 1) {
        int add = (t >= off) ? s[t - off] : 0;
        __syncthreads();
        s[t] += add;
        __syncthreads();
    }
    if (i < N_NODES) {
        int excl = partial[blockIdx.x] + s[t] - v;
        rowptr[i] = excl;
        next[i]   = excl;
    }
    if (i == 0) rowptr[N_NODES] = N_EDGES;
}

__global__ void fill_kernel(const int* __restrict__ src, const int* __restrict__ dst,
                            int* __restrict__ next, int* __restrict__ col) {
    int e = blockIdx.x * blockDim.x + threadIdx.x;
    if (e < N_EDGES) {
        int pos = atomicAdd(&next[dst[e]], 1);
        col[pos] = src[e];
    }
}

// ---- graph ranges from sorted batch: gstart[g] = first node of graph g ----
__global__ void gstart_kernel(const int* __restrict__ batch, int* __restrict__ gstart) {
    int i = blockIdx.x * 256 + threadIdx.x;
    if (i >= N_NODES) return;
    int b = batch[i];
    int prev = (i == 0) ? -1 : batch[i - 1];
    for (int g = prev + 1; g <= b; ++g) gstart[g] = i;
    if (i == N_NODES - 1)
        for (int g = b + 1; g <= N_GRAPHS; ++g) gstart[g] = N_NODES;
}

// ---- weight prep: fp32 [64][64] -> bf16 hi/lo in MFMA B-fragment order ----
__global__ void wprep_kernel(const float* __restrict__ w0, const float* __restrict__ w1,
                             const float* __restrict__ w2, const float* __restrict__ w3,
                             const float* __restrict__ w4, const float* __restrict__ w5,
                             const float* __restrict__ w6, short* __restrict__ out) {
    int tid = blockIdx.x * 256 + threadIdx.x;   // 0 .. 7*4096-1
    int m = tid >> 12, t = tid & 4095;
    const float* W = (m == 0) ? w0 : (m == 1) ? w1 : (m == 2) ? w2 : (m == 3) ? w3
                   : (m == 4) ? w4 : (m == 5) ? w5 : w6;
    int j = t & 7, lane = (t >> 3) & 63, nt = (t >> 9) & 3, kt = t >> 11;
    int k = kt * 32 + ((lane >> 4) << 3) + j;
    int o = nt * 16 + (lane & 15);
    float v = W[k * 64 + o];
    unsigned short hi = bf16rne(v);
    unsigned short lo = bf16rne(v - bf2f(hi));
    out[m * 8192 + t]        = (short)hi;
    out[m * 8192 + 4096 + t] = (short)lo;
}

// ---- pure gather: one wave per node; writes mean row fp32 ----
__global__ __launch_bounds__(512) void gather_kernel(
    const float* __restrict__ h_in, const int* __restrict__ rowptr,
    const int* __restrict__ col, float* __restrict__ meanout) {
    int gw   = (blockIdx.x * 512 + threadIdx.x) >> 6;   // node
    int lane = threadIdx.x & 63;
    int f = lane & 15;
    int g = lane >> 4;
    if (gw >= N_NODES) return;
    int beg = rowptr[gw], end = rowptr[gw + 1];
    const float4* h4 = (const float4*)h_in;

    float4 a0 = make_float4(0.f, 0.f, 0.f, 0.f);
    float4 a1 = a0, a2 = a0, a3 = a0;
    int p = beg + g;
    for (; p + 12 < end; p += 16) {
        int s0 = col[p], s1 = col[p + 4], s2 = col[p + 8], s3 = col[p + 12];
        float4 v0 = h4[s0 * 16 + f];
        float4 v1 = h4[s1 * 16 + f];
        float4 v2 = h4[s2 * 16 + f];
        float4 v3 = h4[s3 * 16 + f];
        a0.x += v0.x; a0.y += v0.y; a0.z += v0.z; a0.w += v0.w;
        a1.x += v1.x; a1.y += v1.y; a1.z += v1.z; a1.w += v1.w;
        a2.x += v2.x; a2.y += v2.y; a2.z += v2.z; a2.w += v2.w;
        a3.x += v3.x; a3.y += v3.y; a3.z += v3.z; a3.w += v3.w;
    }
    for (; p < end; p += 4) {
        float4 v = h4[col[p] * 16 + f];
        a0.x += v.x; a0.y += v.y; a0.z += v.z; a0.w += v.w;
    }
    a0.x += a1.x + a2.x + a3.x;
    a0.y += a1.y + a2.y + a3.y;
    a0.z += a1.z + a2.z + a3.z;
    a0.w += a1.w + a2.w + a3.w;
    a0.x += __shfl_xor(a0.x, 16); a0.y += __shfl_xor(a0.y, 16);
    a0.z += __shfl_xor(a0.z, 16); a0.w += __shfl_xor(a0.w, 16);
    a0.x += __shfl_xor(a0.x, 32); a0.y += __shfl_xor(a0.y, 32);
    a0.z += __shfl_xor(a0.z, 32); a0.w += __shfl_xor(a0.w, 32);
    if (g == 0) {
        float inv = 1.0f / fmaxf((float)(end - beg), 1.0f);
        ((float4*)meanout)[gw * 16 + f] =
            make_float4(a0.x * inv, a0.y * inv, a0.z * inv, a0.w * inv);
    }
}

// ---- per-tile matmul: one wave per 16 nodes; NO atomics. h_out may alias meanin
//      (in-place: tile fully staged before stores; no restrict on those args). ----
__global__ __launch_bounds__(64) void mm_kernel(
    const float* __restrict__ h_in, const float* meanin,
    const short* __restrict__ wl, const short* __restrict__ wr, const short* __restrict__ wm,
    const float* __restrict__ blv, const float* __restrict__ bmv,
    float* h_out) {
    __shared__ short smh[16 * TPAD];
    __shared__ short sml[16 * TPAD];
    __shared__ short sxh[16 * TPAD];
    __shared__ short sxl[16 * TPAD];
    __shared__ short sth[16 * TPAD];
    __shared__ short stl[16 * TPAD];

    int lane = threadIdx.x;
    int f = lane & 15;
    int g = lane >> 4;
    int base = blockIdx.x * 16;
    const float4* h4 = (const float4*)h_in;
    const float4* m4 = (const float4*)meanin;

    // stage 16 rows x 16 float4 for mean and x (coalesced)
#pragma unroll
    for (int i = 0; i < 4; ++i) {
        int idx = i * 64 + lane;
        int r = idx >> 4, c = idx & 15;
        float4 mv = m4[(base + r) * 16 + c];
        float4 xv = h4[(base + r) * 16 + c];
        unsigned short mh0 = bf16rne(mv.x), mh1 = bf16rne(mv.y), mh2 = bf16rne(mv.z), mh3 = bf16rne(mv.w);
        unsigned short xh0 = bf16rne(xv.x), xh1 = bf16rne(xv.y), xh2 = bf16rne(xv.z), xh3 = bf16rne(xv.w);
        uint2 hw, lw;
        hw.x = (unsigned)mh0 | ((unsigned)mh1 << 16);
        hw.y = (unsigned)mh2 | ((unsigned)mh3 << 16);
        lw.x = (unsigned)bf16rne(mv.x - bf2f(mh0)) | ((unsigned)bf16rne(mv.y - bf2f(mh1)) << 16);
        lw.y = (unsigned)bf16rne(mv.z - bf2f(mh2)) | ((unsigned)bf16rne(mv.w - bf2f(mh3)) << 16);
        *(uint2*)&smh[r * TPAD + c * 4] = hw;
        *(uint2*)&sml[r * TPAD + c * 4] = lw;
        hw.x = (unsigned)xh0 | ((unsigned)xh1 << 16);
        hw.y = (unsigned)xh2 | ((unsigned)xh3 << 16);
        lw.x = (unsigned)bf16rne(xv.x - bf2f(xh0)) | ((unsigned)bf16rne(xv.y - bf2f(xh1)) << 16);
        lw.y = (unsigned)bf16rne(xv.z - bf2f(xh2)) | ((unsigned)bf16rne(xv.w - bf2f(xh3)) << 16);
        *(uint2*)&sxh[r * TPAD + c * 4] = hw;
        *(uint2*)&sxl[r * TPAD + c * 4] = lw;
    }

    // A-fragments: lane holds row f, k-chunk g*8 + kt*32
    short8 amh[2], aml[2], axh[2], axl[2];
#pragma unroll
    for (int kt = 0; kt < 2; ++kt) {
        int idx = f * TPAD + kt * 32 + g * 8;
        amh[kt] = *(const short8*)&smh[idx];
        aml[kt] = *(const short8*)&sml[idx];
        axh[kt] = *(const short8*)&sxh[idx];
        axl[kt] = *(const short8*)&sxl[idx];
    }
    const short* wlh = wl;
    const short* wll = wl + 4096;
    const short* wrh = wr;
    const short* wrl = wr + 4096;

    // ---- mat1: t = mean@Wl + bl + x@Wr ----
#pragma unroll
    for (int nt = 0; nt < 4; ++nt) {
        f32x4 acc = {0.f, 0.f, 0.f, 0.f};
#pragma unroll
        for (int kt = 0; kt < 2; ++kt) {
            int fi = ((kt * 4 + nt) * 64 + lane) * 8;
            short8 blh = *(const short8*)&wlh[fi];
            short8 bll = *(const short8*)&wll[fi];
            short8 brh = *(const short8*)&wrh[fi];
            short8 brl = *(const short8*)&wrl[fi];
            acc = MFMA16(amh[kt], blh, acc);
            acc = MFMA16(aml[kt], blh, acc);
            acc = MFMA16(amh[kt], bll, acc);
            acc = MFMA16(axh[kt], brh, acc);
            acc = MFMA16(axl[kt], brh, acc);
            acc = MFMA16(axh[kt], brl, acc);
        }
        float bias = blv[nt * 16 + f];
#pragma unroll
        for (int r = 0; r < 4; ++r) {
            float tv = acc[r] + bias;
            unsigned short hi = bf16rne(tv);
            unsigned short lo = bf16rne(tv - bf2f(hi));
            int row = g * 4 + r;   // C layout: row=(lane>>4)*4+r, col=lane&15
            sth[row * TPAD + nt * 16 + f] = (short)hi;
            stl[row * TPAD + nt * 16 + f] = (short)lo;
        }
    }

    // ---- mat2: h = relu(t@Wm + bm) ----
    short8 ath[2], atl[2];
#pragma unroll
    for (int kt = 0; kt < 2; ++kt) {
        int idx = f * TPAD + kt * 32 + g * 8;
        ath[kt] = *(const short8*)&sth[idx];
        atl[kt] = *(const short8*)&stl[idx];
    }
    const short* wmh = wm;
    const short* wml = wm + 4096;
#pragma unroll
    for (int nt = 0; nt < 4; ++nt) {
        f32x4 acc = {0.f, 0.f, 0.f, 0.f};
#pragma unroll
        for (int kt = 0; kt < 2; ++kt) {
            int fi = ((kt * 4 + nt) * 64 + lane) * 8;
            short8 bh  = *(const short8*)&wmh[fi];
            short8 bl2 = *(const short8*)&wml[fi];
            acc = MFMA16(ath[kt], bh, acc);
            acc = MFMA16(atl[kt], bh, acc);
            acc = MFMA16(ath[kt], bl2, acc);
        }
        float bias = bmv[nt * 16 + f];
#pragma unroll
        for (int r = 0; r < 4; ++r) {
            float hv = acc[r] + bias;
            hv = hv > 0.f ? hv : 0.f;
            int row  = g * 4 + r;
            int node = base + row;
            h_out[node * D + nt * 16 + f] = hv;
        }
    }
}

// ---- fused segmented mean-pool + MLP: one block (4 waves) per graph ----
__global__ __launch_bounds__(256) void poolmlp_kernel(
    const float* __restrict__ h0, const float* __restrict__ h1, const float* __restrict__ h2,
    const int* __restrict__ gstart,
    const float* __restrict__ W1, const float* __restrict__ b1,
    const float* __restrict__ W2, const float* __restrict__ b2,
    float* __restrict__ out) {
    __shared__ float spart[4][3][64];
    __shared__ float sg[3 * 64];
    __shared__ float tt[64];
    int gr = blockIdx.x;
    int w = threadIdx.x >> 6, lane = threadIdx.x & 63;
    int beg = gstart[gr], end = gstart[gr + 1];
    float s0 = 0.f, s1 = 0.f, s2 = 0.f;
    for (int n = beg + w; n < end; n += 4) {
        s0 += h0[n * 64 + lane];
        s1 += h1[n * 64 + lane];
        s2 += h2[n * 64 + lane];
    }
    spart[w][0][lane] = s0; spart[w][1][lane] = s1; spart[w][2][lane] = s2;
    __syncthreads();
    if (w == 0) {
        float inv = 1.0f / fmaxf((float)(end - beg), 1.0f);
#pragma unroll
        for (int l = 0; l < 3; ++l)
            sg[l * 64 + lane] = (spart[0][l][lane] + spart[1][l][lane] +
                                 spart[2][l][lane] + spart[3][l][lane]) * inv;
    }
    __syncthreads();
    if (w == 0) {
        float acc = b1[lane];
#pragma unroll 8
        for (int k = 0; k < 3 * 64; ++k) acc += sg[k] * W1[k * 64 + lane];
        tt[lane] = fmaxf(acc, 0.f);
    }
    __syncthreads();
    if (w == 0 && lane < D_TARGET) {
        float acc = b2[lane];
#pragma unroll
        for (int k = 0; k < 64; ++k) acc += tt[k] * W2[k * D_TARGET + lane];
        out[gr * D_TARGET + lane] = acc;
    }
}

extern "C" void kernel_launch(void* const* d_in, const int* in_sizes, int n_in,
                              void* d_out, int out_size, void* d_ws, size_t ws_size,
                              hipStream_t stream) {
    const float* x     = (const float*)d_in[0];
    const int*   ei    = (const int*)d_in[1];
    const int*   src   = ei;
    const int*   dst   = ei + N_EDGES;
    const int*   batch = (const int*)d_in[2];

    const float* Wl[3] = {(const float*)d_in[3], (const float*)d_in[6], (const float*)d_in[9]};
    const float* bl[3] = {(const float*)d_in[4], (const float*)d_in[7], (const float*)d_in[10]};
    const float* Wr[3] = {(const float*)d_in[5], (const float*)d_in[8], (const float*)d_in[11]};
    const float* Wm = (const float*)d_in[12];
    const float* bm = (const float*)d_in[13];
    const float* W1 = (const float*)d_in[14];
    const float* b1 = (const float*)d_in[15];
    const float* W2 = (const float*)d_in[16];
    const float* b2 = (const float*)d_in[17];

    // workspace layout (4-byte words)
    int*   degi    = (int*)d_ws;                       // 50000
    int*   partial = degi + N_NODES;                   // 256
    int*   rowptr  = partial + 256;                    // 50001
    int*   next    = rowptr + N_NODES + 1;             // 50000
    int*   gstart  = next + N_NODES;                   // 513 (+3 pad -> 516)
    int*   col     = gstart + 516;                     // 800000
    short* wfrag   = (short*)(col + N_EDGES + 3);      // pad -> 16B aligned; 7*8192 shorts
    float* m0      = (float*)(wfrag + 7 * 8192);       // 3,200,000 (mean_l then h_l in place)
    float* m1      = m0 + (size_t)N_NODES * D;         // 3,200,000
    float* m2      = m1 + (size_t)N_NODES * D;         // 3,200,000   (~42 MB total)

    hipMemsetAsync(degi, 0, N_NODES * sizeof(int), stream);

    count_kernel<<<(N_EDGES + 255) / 256, 256, 0, stream>>>(dst, degi);
    scan_partials<<<NB_SCAN, 256, 0, stream>>>(degi, partial);
    scan_offsets<<<1, 64, 0, stream>>>(partial);
    scan_final<<<NB_SCAN, 256, 0, stream>>>(degi, partial, rowptr, next);
    fill_kernel<<<(N_EDGES + 255) / 256, 256, 0, stream>>>(src, dst, next, col);
    gstart_kernel<<<NB_SCAN, 256, 0, stream>>>(batch, gstart);
    wprep_kernel<<<7 * 4096 / 256, 256, 0, stream>>>(
        Wl[0], Wr[0], Wl[1], Wr[1], Wl[2], Wr[2], Wm, wfrag);

    float* mb[3] = {m0, m1, m2};
    const float* hin = x;
    for (int l = 0; l < 3; ++l) {
        gather_kernel<<<(N_NODES * 64 + 511) / 512, 512, 0, stream>>>(hin, rowptr, col, mb[l]);
        mm_kernel<<<N_NODES / 16, 64, 0, stream>>>(
            hin, mb[l],
            wfrag + (2 * l) * 8192, wfrag + (2 * l + 1) * 8192, wfrag + 6 * 8192,
            bl[l], bm, mb[l]);   // in-place: h_l overwrites mean_l
        hin = mb[l];
    }

    poolmlp_kernel<<<N_GRAPHS, 256, 0, stream>>>(m0, m1, m2, gstart, W1, b1, W2, b2,
                                                 (float*)d_out);
}

// Round 10
// 222.016 us; speedup vs baseline: 2.1833x; 1.1784x over previous
//
#include <hip/hip_runtime.h>

// GraphSAGE forward: bf16-plane storage (halved gather traffic, L2-resident),
// uint16 CSR col, atomic-free pooling, bf16x3-split MFMA matmuls.
#define N_NODES 50000
#define N_EDGES 800000
#define D 64
#define N_GRAPHS 512
#define D_TARGET 10
#define NB_SCAN ((N_NODES + 255) / 256)   // 196
#define TPAD 72                            // LDS tile row stride in bf16 (144B rows, 16B-aligned)

typedef __attribute__((ext_vector_type(8))) short short8;
typedef __attribute__((ext_vector_type(4))) float f32x4;
typedef unsigned short ushort_t;
#define MFMA16(a, b, c) __builtin_amdgcn_mfma_f32_16x16x32_bf16(a, b, c, 0, 0, 0)

__device__ inline unsigned short bf16rne(float f) {
    unsigned u = __builtin_bit_cast(unsigned, f);
    u += 0x7FFFu + ((u >> 16) & 1u);
    return (unsigned short)(u >> 16);
}
__device__ inline float bf2f(unsigned short h) {
    unsigned u = ((unsigned)h) << 16;
    return __builtin_bit_cast(float, u);
}
// accumulate 8 bf16 (packed in uint4) into 8 fp32
__device__ inline void acc8(float* a, uint4 v) {
    a[0] += __builtin_bit_cast(float, v.x << 16);
    a[1] += __builtin_bit_cast(float, v.x & 0xFFFF0000u);
    a[2] += __builtin_bit_cast(float, v.y << 16);
    a[3] += __builtin_bit_cast(float, v.y & 0xFFFF0000u);
    a[4] += __builtin_bit_cast(float, v.z << 16);
    a[5] += __builtin_bit_cast(float, v.z & 0xFFFF0000u);
    a[6] += __builtin_bit_cast(float, v.w << 16);
    a[7] += __builtin_bit_cast(float, v.w & 0xFFFF0000u);
}

// ---- int degree histogram ----
__global__ void count_kernel(const int* __restrict__ dst, int* __restrict__ degi) {
    int i = blockIdx.x * blockDim.x + threadIdx.x;
    if (i < N_EDGES) atomicAdd(&degi[dst[i]], 1);
}

__global__ void scan_partials(const int* __restrict__ degi, int* __restrict__ partial) {
    __shared__ int s[256];
    int t = threadIdx.x;
    int i = blockIdx.x * 256 + t;
    s[t] = (i < N_NODES) ? degi[i] : 0;
    __syncthreads();
    for (int off = 128; off > 0; off >>= 1) {
        if (t < off) s[t] += s[t + off];
        __syncthreads();
    }
    if (t == 0) partial[blockIdx.x] = s[0];
}

__global__ void scan_offsets(int* __restrict__ partial) {
    if (threadIdx.x == 0) {
        int run = 0;
        for (int i = 0; i < NB_SCAN; ++i) { int p = partial[i]; partial[i] = run; run += p; }
    }
}

__global__ void scan_final(const int* __restrict__ degi, const int* __restrict__ partial,
                           int* __restrict__ rowptr, int* __restrict__ next) {
    __shared__ int s[256];
    int t = threadIdx.x;
    int i = blockIdx.x * 256 + t;
    int v = (i < N_NODES) ? degi[i] : 0;
    s[t] = v;
    __syncthreads();
    for (int off = 1; off < 256; off <<= 1) {
        int add = (t >= off) ? s[t - off] : 0;
        __syncthreads();
        s[t] += add;
        __syncthreads();
    }
    if (i < N_NODES) {
        int excl = partial[blockIdx.x] + s[t] - v;
        rowptr[i] = excl;
        next[i]   = excl;
    }
    if (i == 0) rowptr[N_NODES] = N_EDGES;
}

// ---- CSR fill: col16[pos] = src (uint16) ----
__global__ void fill_kernel(const int* __restrict__ src, const int* __restrict__ dst,
                            int* __restrict__ next, ushort_t* __restrict__ col) {
    int e = blockIdx.x * blockDim.x + threadIdx.x;
    if (e < N_EDGES) {
        int pos = atomicAdd(&next[dst[e]], 1);
        col[pos] = (ushort_t)src[e];
    }
}

// ---- graph ranges from sorted batch ----
__global__ void gstart_kernel(const int* __restrict__ batch, int* __restrict__ gstart) {
    int i = blockIdx.x * 256 + threadIdx.x;
    if (i >= N_NODES) return;
    int b = batch[i];
    int prev = (i == 0) ? -1 : batch[i - 1];
    for (int g = prev + 1; g <= b; ++g) gstart[g] = i;
    if (i == N_NODES - 1)
        for (int g = b + 1; g <= N_GRAPHS; ++g) gstart[g] = N_NODES;
}

// ---- weight prep: fp32 [64][64] -> bf16 hi/lo in MFMA B-fragment order ----
__global__ void wprep_kernel(const float* __restrict__ w0, const float* __restrict__ w1,
                             const float* __restrict__ w2, const float* __restrict__ w3,
                             const float* __restrict__ w4, const float* __restrict__ w5,
                             const float* __restrict__ w6, short* __restrict__ out) {
    int tid = blockIdx.x * 256 + threadIdx.x;   // 0 .. 7*4096-1
    int m = tid >> 12, t = tid & 4095;
    const float* W = (m == 0) ? w0 : (m == 1) ? w1 : (m == 2) ? w2 : (m == 3) ? w3
                   : (m == 4) ? w4 : (m == 5) ? w5 : w6;
    int j = t & 7, lane = (t >> 3) & 63, nt = (t >> 9) & 3, kt = t >> 11;
    int k = kt * 32 + ((lane >> 4) << 3) + j;
    int o = nt * 16 + (lane & 15);
    float v = W[k * 64 + o];
    unsigned short hi = bf16rne(v);
    unsigned short lo = bf16rne(v - bf2f(hi));
    out[m * 8192 + t]        = (short)hi;
    out[m * 8192 + 4096 + t] = (short)lo;
}

// ---- x (fp32) -> bf16 plane (for layer-1 gather) ----
__global__ void xsplit_kernel(const float* __restrict__ x, ushort_t* __restrict__ xh) {
    int i = blockIdx.x * 256 + threadIdx.x;
    if (i < N_NODES * D) xh[i] = bf16rne(x[i]);
}

// ---- pure gather over bf16 plane: one wave per node; 8 subgroups x 8 lanes;
//      writes mean as bf16 hi/lo planes (fp32-accumulated). ----
__global__ __launch_bounds__(512) void gather_kernel(
    const ushort_t* __restrict__ hplane, const int* __restrict__ rowptr,
    const ushort_t* __restrict__ col,
    ushort_t* __restrict__ mh, ushort_t* __restrict__ ml) {
    int gw   = (blockIdx.x * 512 + threadIdx.x) >> 6;   // node
    int lane = threadIdx.x & 63;
    int f = lane & 7;    // 16B chunk within 128B row (8 bf16)
    int g = lane >> 3;   // subgroup 0..7
    if (gw >= N_NODES) return;
    int beg = rowptr[gw], end = rowptr[gw + 1];
    const uint4* h16 = (const uint4*)hplane;   // row = 8 uint4 chunks

    float a[8] = {0.f, 0.f, 0.f, 0.f, 0.f, 0.f, 0.f, 0.f};
    float b[8] = {0.f, 0.f, 0.f, 0.f, 0.f, 0.f, 0.f, 0.f};
    int p = beg + g;
    for (; p + 8 < end; p += 16) {
        int s0 = col[p], s1 = col[p + 8];
        uint4 v0 = h16[s0 * 8 + f];
        uint4 v1 = h16[s1 * 8 + f];
        acc8(a, v0);
        acc8(b, v1);
    }
    if (p < end) {
        uint4 v = h16[col[p] * 8 + f];
        acc8(a, v);
    }
#pragma unroll
    for (int j = 0; j < 8; ++j) {
        float v = a[j] + b[j];
        v += __shfl_xor(v, 8);
        v += __shfl_xor(v, 16);
        v += __shfl_xor(v, 32);
        a[j] = v;
    }
    if (g == 0) {
        float inv = 1.0f / fmaxf((float)(end - beg), 1.0f);
        unsigned hws[4], lws[4];
#pragma unroll
        for (int i = 0; i < 4; ++i) {
            float v0 = a[2 * i] * inv, v1 = a[2 * i + 1] * inv;
            unsigned short h0 = bf16rne(v0), h1 = bf16rne(v1);
            hws[i] = (unsigned)h0 | ((unsigned)h1 << 16);
            lws[i] = (unsigned)bf16rne(v0 - bf2f(h0)) |
                     ((unsigned)bf16rne(v1 - bf2f(h1)) << 16);
        }
        uint4 hv = {hws[0], hws[1], hws[2], hws[3]};
        uint4 lv = {lws[0], lws[1], lws[2], lws[3]};
        ((uint4*)mh)[gw * 8 + f] = hv;
        ((uint4*)ml)[gw * 8 + f] = lv;
    }
}

// ---- per-tile matmul: one wave per 16 nodes; no atomics.
// XMODE 0: root x from fp32 (layer 1, hi/lo split).  XMODE 1: root from bf16 h plane (exact).
template <int XMODE>
__global__ __launch_bounds__(64) void mm_kernel(
    const float* __restrict__ xf, const ushort_t* __restrict__ xhp,
    const ushort_t* __restrict__ mh, const ushort_t* __restrict__ ml,
    const short* __restrict__ wl, const short* __restrict__ wr, const short* __restrict__ wm,
    const float* __restrict__ blv, const float* __restrict__ bmv,
    ushort_t* __restrict__ hhout) {
    __shared__ short smh[16 * TPAD];
    __shared__ short sml[16 * TPAD];
    __shared__ short sxh[16 * TPAD];
    __shared__ short sxl[16 * TPAD];
    __shared__ short sth[16 * TPAD];
    __shared__ short stl[16 * TPAD];

    int lane = threadIdx.x;
    int f = lane & 15;
    int g = lane >> 4;
    int base = blockIdx.x * 16;

    // stage mean hi/lo planes (bf16 direct copy, coalesced)
    {
        const uint4* mh16 = (const uint4*)mh;
        const uint4* ml16 = (const uint4*)ml;
#pragma unroll
        for (int i = 0; i < 2; ++i) {
            int c = i * 64 + lane;        // chunk 0..127
            int r = c >> 3, cc = c & 7;
            *(uint4*)&smh[r * TPAD + cc * 8] = mh16[(base + r) * 8 + cc];
            *(uint4*)&sml[r * TPAD + cc * 8] = ml16[(base + r) * 8 + cc];
        }
    }
    if (XMODE == 1) {
        const uint4* xh16 = (const uint4*)xhp;
#pragma unroll
        for (int i = 0; i < 2; ++i) {
            int c = i * 64 + lane;
            int r = c >> 3, cc = c & 7;
            *(uint4*)&sxh[r * TPAD + cc * 8] = xh16[(base + r) * 8 + cc];
        }
    } else {
        const float4* x4 = (const float4*)xf;
#pragma unroll
        for (int i = 0; i < 4; ++i) {
            int idx = i * 64 + lane;
            int r = idx >> 4, c = idx & 15;
            float4 xv = x4[(size_t)(base + r) * 16 + c];
            unsigned short h0 = bf16rne(xv.x), h1 = bf16rne(xv.y),
                           h2 = bf16rne(xv.z), h3 = bf16rne(xv.w);
            uint2 hw, lw;
            hw.x = (unsigned)h0 | ((unsigned)h1 << 16);
            hw.y = (unsigned)h2 | ((unsigned)h3 << 16);
            lw.x = (unsigned)bf16rne(xv.x - bf2f(h0)) | ((unsigned)bf16rne(xv.y - bf2f(h1)) << 16);
            lw.y = (unsigned)bf16rne(xv.z - bf2f(h2)) | ((unsigned)bf16rne(xv.w - bf2f(h3)) << 16);
            *(uint2*)&sxh[r * TPAD + c * 4] = hw;
            *(uint2*)&sxl[r * TPAD + c * 4] = lw;
        }
    }
    // wave-local LDS: same wave produces and consumes; compiler inserts lgkmcnt waits.

    // A-fragments: lane holds row f, k-chunk g*8 + kt*32
    short8 amh[2], aml[2], axh[2], axl[2];
#pragma unroll
    for (int kt = 0; kt < 2; ++kt) {
        int idx = f * TPAD + kt * 32 + g * 8;
        amh[kt] = *(const short8*)&smh[idx];
        aml[kt] = *(const short8*)&sml[idx];
        axh[kt] = *(const short8*)&sxh[idx];
        if (XMODE == 0) axl[kt] = *(const short8*)&sxl[idx];
    }
    const short* wlh = wl;
    const short* wll = wl + 4096;
    const short* wrh = wr;
    const short* wrl = wr + 4096;

    // ---- mat1: t = mean@Wl + bl + x@Wr ----
#pragma unroll
    for (int nt = 0; nt < 4; ++nt) {
        f32x4 acc = {0.f, 0.f, 0.f, 0.f};
#pragma unroll
        for (int kt = 0; kt < 2; ++kt) {
            int fi = ((kt * 4 + nt) * 64 + lane) * 8;
            short8 blh = *(const short8*)&wlh[fi];
            short8 bll = *(const short8*)&wll[fi];
            short8 brh = *(const short8*)&wrh[fi];
            short8 brl = *(const short8*)&wrl[fi];
            acc = MFMA16(amh[kt], blh, acc);
            acc = MFMA16(aml[kt], blh, acc);
            acc = MFMA16(amh[kt], bll, acc);
            acc = MFMA16(axh[kt], brh, acc);
            if (XMODE == 0) acc = MFMA16(axl[kt], brh, acc);
            acc = MFMA16(axh[kt], brl, acc);
        }
        float bias = blv[nt * 16 + f];
#pragma unroll
        for (int r = 0; r < 4; ++r) {
            float tv = acc[r] + bias;
            unsigned short hi = bf16rne(tv);
            unsigned short lo = bf16rne(tv - bf2f(hi));
            int row = g * 4 + r;   // C layout: row=(lane>>4)*4+r, col=lane&15
            sth[row * TPAD + nt * 16 + f] = (short)hi;
            stl[row * TPAD + nt * 16 + f] = (short)lo;
        }
    }

    // ---- mat2: h = relu(t@Wm + bm) -> bf16 plane ----
    short8 ath[2], atl[2];
#pragma unroll
    for (int kt = 0; kt < 2; ++kt) {
        int idx = f * TPAD + kt * 32 + g * 8;
        ath[kt] = *(const short8*)&sth[idx];
        atl[kt] = *(const short8*)&stl[idx];
    }
    const short* wmh = wm;
    const short* wml = wm + 4096;
#pragma unroll
    for (int nt = 0; nt < 4; ++nt) {
        f32x4 acc = {0.f, 0.f, 0.f, 0.f};
#pragma unroll
        for (int kt = 0; kt < 2; ++kt) {
            int fi = ((kt * 4 + nt) * 64 + lane) * 8;
            short8 bh  = *(const short8*)&wmh[fi];
            short8 bl2 = *(const short8*)&wml[fi];
            acc = MFMA16(ath[kt], bh, acc);
            acc = MFMA16(atl[kt], bh, acc);
            acc = MFMA16(ath[kt], bl2, acc);
        }
        float bias = bmv[nt * 16 + f];
#pragma unroll
        for (int r = 0; r < 4; ++r) {
            float hv = acc[r] + bias;
            hv = hv > 0.f ? hv : 0.f;
            int row  = g * 4 + r;
            int node = base + row;
            hhout[node * D + nt * 16 + f] = bf16rne(hv);
        }
    }
}

// ---- fused segmented mean-pool + MLP over bf16 h planes ----
__global__ __launch_bounds__(256) void poolmlp_kernel(
    const ushort_t* __restrict__ h0, const ushort_t* __restrict__ h1,
    const ushort_t* __restrict__ h2, const int* __restrict__ gstart,
    const float* __restrict__ W1, const float* __restrict__ b1,
    const float* __restrict__ W2, const float* __restrict__ b2,
    float* __restrict__ out) {
    __shared__ float spart[4][3][64];
    __shared__ float sg[3 * 64];
    __shared__ float tt[64];
    int gr = blockIdx.x;
    int w = threadIdx.x >> 6, lane = threadIdx.x & 63;
    int beg = gstart[gr], end = gstart[gr + 1];
    float s0 = 0.f, s1 = 0.f, s2 = 0.f;
    for (int n = beg + w; n < end; n += 4) {
        s0 += bf2f(h0[n * 64 + lane]);
        s1 += bf2f(h1[n * 64 + lane]);
        s2 += bf2f(h2[n * 64 + lane]);
    }
    spart[w][0][lane] = s0; spart[w][1][lane] = s1; spart[w][2][lane] = s2;
    __syncthreads();
    if (w == 0) {
        float inv = 1.0f / fmaxf((float)(end - beg), 1.0f);
#pragma unroll
        for (int l = 0; l < 3; ++l)
            sg[l * 64 + lane] = (spart[0][l][lane] + spart[1][l][lane] +
                                 spart[2][l][lane] + spart[3][l][lane]) * inv;
    }
    __syncthreads();
    if (w == 0) {
        float acc = b1[lane];
#pragma unroll 8
        for (int k = 0; k < 3 * 64; ++k) acc += sg[k] * W1[k * 64 + lane];
        tt[lane] = fmaxf(acc, 0.f);
    }
    __syncthreads();
    if (w == 0 && lane < D_TARGET) {
        float acc = b2[lane];
#pragma unroll
        for (int k = 0; k < 64; ++k) acc += tt[k] * W2[k * D_TARGET + lane];
        out[gr * D_TARGET + lane] = acc;
    }
}

extern "C" void kernel_launch(void* const* d_in, const int* in_sizes, int n_in,
                              void* d_out, int out_size, void* d_ws, size_t ws_size,
                              hipStream_t stream) {
    const float* x     = (const float*)d_in[0];
    const int*   ei    = (const int*)d_in[1];
    const int*   src   = ei;
    const int*   dst   = ei + N_EDGES;
    const int*   batch = (const int*)d_in[2];

    const float* Wl[3] = {(const float*)d_in[3], (const float*)d_in[6], (const float*)d_in[9]};
    const float* bl[3] = {(const float*)d_in[4], (const float*)d_in[7], (const float*)d_in[10]};
    const float* Wr[3] = {(const float*)d_in[5], (const float*)d_in[8], (const float*)d_in[11]};
    const float* Wm = (const float*)d_in[12];
    const float* bm = (const float*)d_in[13];
    const float* W1 = (const float*)d_in[14];
    const float* b1 = (const float*)d_in[15];
    const float* W2 = (const float*)d_in[16];
    const float* b2 = (const float*)d_in[17];

    // workspace layout (4-byte words; each section 16B-aligned)
    int*      degi    = (int*)d_ws;                       // 50000
    int*      partial = degi + 50000;                     // 256
    int*      rowptr  = partial + 256;                    // 50001 -> pad 50008
    int*      next    = rowptr + 50008;                   // 50000
    int*      gstart  = next + 50000;                     // 513 -> pad 520
    short*    wfrag   = (short*)(gstart + 520);           // 7*8192 shorts = 28672 ints
    ushort_t* col     = (ushort_t*)(wfrag + 7 * 8192);    // 800000 ushort = 400000 ints
    ushort_t* xh      = col + 800000;                     // 3.2M ushort
    ushort_t* mh      = xh + (size_t)N_NODES * D;         // 3.2M
    ushort_t* ml      = mh + (size_t)N_NODES * D;         // 3.2M
    ushort_t* hh0     = ml + (size_t)N_NODES * D;         // 3.2M
    ushort_t* hh1     = hh0 + (size_t)N_NODES * D;        // 3.2M
    ushort_t* hh2     = hh1 + (size_t)N_NODES * D;        // 3.2M   (~41 MB total)

    hipMemsetAsync(degi, 0, 50000 * sizeof(int), stream);

    count_kernel<<<(N_EDGES + 255) / 256, 256, 0, stream>>>(dst, degi);
    scan_partials<<<NB_SCAN, 256, 0, stream>>>(degi, partial);
    scan_offsets<<<1, 64, 0, stream>>>(partial);
    scan_final<<<NB_SCAN, 256, 0, stream>>>(degi, partial, rowptr, next);
    fill_kernel<<<(N_EDGES + 255) / 256, 256, 0, stream>>>(src, dst, next, col);
    gstart_kernel<<<NB_SCAN, 256, 0, stream>>>(batch, gstart);
    wprep_kernel<<<7 * 4096 / 256, 256, 0, stream>>>(
        Wl[0], Wr[0], Wl[1], Wr[1], Wl[2], Wr[2], Wm, wfrag);
    xsplit_kernel<<<(N_NODES * D + 255) / 256, 256, 0, stream>>>(x, xh);

    ushort_t* hplanes[4] = {xh, hh0, hh1, hh2};
    for (int l = 0; l < 3; ++l) {
        gather_kernel<<<(N_NODES * 64 + 511) / 512, 512, 0, stream>>>(
            hplanes[l], rowptr, col, mh, ml);
        if (l == 0)
            mm_kernel<0><<<N_NODES / 16, 64, 0, stream>>>(
                x, nullptr, mh, ml,
                wfrag + 0 * 8192, wfrag + 1 * 8192, wfrag + 6 * 8192,
                bl[0], bm, hh0);
        else
            mm_kernel<1><<<N_NODES / 16, 64, 0, stream>>>(
                nullptr, hplanes[l], mh, ml,
                wfrag + (2 * l) * 8192, wfrag + (2 * l + 1) * 8192, wfrag + 6 * 8192,
                bl[l], bm, hplanes[l + 1]);
    }

    poolmlp_kernel<<<N_GRAPHS, 256, 0, stream>>>(hh0, hh1, hh2, gstart, W1, b1, W2, b2,
                                                 (float*)d_out);
}

// Round 11
// 214.378 us; speedup vs baseline: 2.2611x; 1.0356x over previous
//
#include <hip/hip_runtime.h>

// GraphSAGE forward: bf16-plane storage, uint16 CSR col, binned CSR fill,
// fused small kernels, atomic-free pooling, bf16x3-split MFMA matmuls.
#define N_NODES 50000
#define N_EDGES 800000
#define D 64
#define N_GRAPHS 512
#define D_TARGET 10
#define NB_SCAN ((N_NODES + 255) / 256)   // 196
#define TPAD 72                            // LDS tile row stride in bf16
#define NBIN 8
#define NODES_PER_BIN (N_NODES / NBIN)     // 6250
#define EDGE_BLOCKS (N_EDGES / 256)        // 3125 (exact)
#define FILL_BLOCKS (NBIN * EDGE_BLOCKS)   // 25000
#define XSPLIT_BLOCKS EDGE_BLOCKS          // 3125 (one float4/thread, exact)
#define WPREP_BLOCKS 112                   // 7*4096/256

typedef __attribute__((ext_vector_type(8))) short short8;
typedef __attribute__((ext_vector_type(4))) float f32x4;
typedef unsigned short ushort_t;
#define MFMA16(a, b, c) __builtin_amdgcn_mfma_f32_16x16x32_bf16(a, b, c, 0, 0, 0)

__device__ inline unsigned short bf16rne(float f) {
    unsigned u = __builtin_bit_cast(unsigned, f);
    u += 0x7FFFu + ((u >> 16) & 1u);
    return (unsigned short)(u >> 16);
}
__device__ inline float bf2f(unsigned short h) {
    unsigned u = ((unsigned)h) << 16;
    return __builtin_bit_cast(float, u);
}
__device__ inline void acc8(float* a, uint4 v) {
    a[0] += __builtin_bit_cast(float, v.x << 16);
    a[1] += __builtin_bit_cast(float, v.x & 0xFFFF0000u);
    a[2] += __builtin_bit_cast(float, v.y << 16);
    a[3] += __builtin_bit_cast(float, v.y & 0xFFFF0000u);
    a[4] += __builtin_bit_cast(float, v.z << 16);
    a[5] += __builtin_bit_cast(float, v.z & 0xFFFF0000u);
    a[6] += __builtin_bit_cast(float, v.w << 16);
    a[7] += __builtin_bit_cast(float, v.w & 0xFFFF0000u);
}

// ---- K1: degree histogram (blocks 0..3124) + graph ranges (blocks 3125..3320) ----
__global__ void k1_kernel(const int* __restrict__ dst, const int* __restrict__ batch,
                          int* __restrict__ degi, int* __restrict__ gstart) {
    int b = blockIdx.x;
    if (b < EDGE_BLOCKS) {
        int e = b * 256 + threadIdx.x;   // exact, no guard
        atomicAdd(&degi[dst[e]], 1);
    } else {
        int i = (b - EDGE_BLOCKS) * 256 + threadIdx.x;
        if (i >= N_NODES) return;
        int bb = batch[i];
        int prev = (i == 0) ? -1 : batch[i - 1];
        for (int g = prev + 1; g <= bb; ++g) gstart[g] = i;
        if (i == N_NODES - 1)
            for (int g = bb + 1; g <= N_GRAPHS; ++g) gstart[g] = N_NODES;
    }
}

// ---- K2: per-256-chunk sums ----
__global__ void scan_partials(const int* __restrict__ degi, int* __restrict__ partial) {
    __shared__ int s[256];
    int t = threadIdx.x;
    int i = blockIdx.x * 256 + t;
    s[t] = (i < N_NODES) ? degi[i] : 0;
    __syncthreads();
    for (int off = 128; off > 0; off >>= 1) {
        if (t < off) s[t] += s[t + off];
        __syncthreads();
    }
    if (t == 0) partial[blockIdx.x] = s[0];
}

// ---- K3: per-chunk inclusive scan with inline partial-prefix reduction ----
__global__ void scan_final(const int* __restrict__ degi, const int* __restrict__ partial,
                           int* __restrict__ rowptr, int* __restrict__ next) {
    __shared__ int s[256];
    __shared__ int sp[256];
    int t = threadIdx.x;
    int i = blockIdx.x * 256 + t;
    sp[t] = (t < blockIdx.x) ? partial[t] : 0;   // blockIdx.x <= 195 < 256
    __syncthreads();
    for (int off = 128; off > 0; off >>= 1) {
        if (t < off) sp[t] += sp[t + off];
        __syncthreads();
    }
    int prefix = sp[0];
    int v = (i < N_NODES) ? degi[i] : 0;
    s[t] = v;
    __syncthreads();
    for (int off = 1; off < 256; off <<= 1) {
        int add = (t >= off) ? s[t - off] : 0;
        __syncthreads();
        s[t] += add;
        __syncthreads();
    }
    if (i < N_NODES) {
        int excl = prefix + s[t] - v;
        rowptr[i] = excl;
        next[i]   = excl;
    }
    if (i == 0) rowptr[N_NODES] = N_EDGES;
}

// ---- K4: binned CSR fill (blocks 0..24999) + x->bf16 (3125) + weight prep (112) ----
__global__ void k4_kernel(const int* __restrict__ src, const int* __restrict__ dst,
                          int* __restrict__ next, ushort_t* __restrict__ col,
                          const float* __restrict__ x, ushort_t* __restrict__ xh,
                          const float* __restrict__ w0, const float* __restrict__ w1,
                          const float* __restrict__ w2, const float* __restrict__ w3,
                          const float* __restrict__ w4, const float* __restrict__ w5,
                          const float* __restrict__ w6, short* __restrict__ wfrag) {
    int b = blockIdx.x;
    if (b < FILL_BLOCKS) {
        int bin = b / EDGE_BLOCKS;
        int e = (b % EDGE_BLOCKS) * 256 + threadIdx.x;   // exact
        int d = dst[e];
        int lo = bin * NODES_PER_BIN;
        if (d >= lo && d < lo + NODES_PER_BIN) {
            int pos = atomicAdd(&next[d], 1);
            col[pos] = (ushort_t)src[e];
        }
    } else if (b < FILL_BLOCKS + XSPLIT_BLOCKS) {
        int idx = (b - FILL_BLOCKS) * 256 + threadIdx.x;   // float4 index, exact
        float4 v = ((const float4*)x)[idx];
        ushort4 o;
        o.x = bf16rne(v.x); o.y = bf16rne(v.y); o.z = bf16rne(v.z); o.w = bf16rne(v.w);
        ((ushort4*)xh)[idx] = o;
    } else {
        int tid = (b - FILL_BLOCKS - XSPLIT_BLOCKS) * 256 + threadIdx.x;  // 0..7*4096-1
        int m = tid >> 12, t = tid & 4095;
        const float* W = (m == 0) ? w0 : (m == 1) ? w1 : (m == 2) ? w2 : (m == 3) ? w3
                       : (m == 4) ? w4 : (m == 5) ? w5 : w6;
        int j = t & 7, lane = (t >> 3) & 63, nt = (t >> 9) & 3, kt = t >> 11;
        int k = kt * 32 + ((lane >> 4) << 3) + j;
        int o = nt * 16 + (lane & 15);
        float v = W[k * 64 + o];
        unsigned short hi = bf16rne(v);
        unsigned short lo = bf16rne(v - bf2f(hi));
        wfrag[m * 8192 + t]        = (short)hi;
        wfrag[m * 8192 + 4096 + t] = (short)lo;
    }
}

// ---- pure gather over bf16 plane: one wave per node; 8 subgroups x 8 lanes ----
__global__ __launch_bounds__(512) void gather_kernel(
    const ushort_t* __restrict__ hplane, const int* __restrict__ rowptr,
    const ushort_t* __restrict__ col,
    ushort_t* __restrict__ mh, ushort_t* __restrict__ ml) {
    int gw   = (blockIdx.x * 512 + threadIdx.x) >> 6;   // node
    int lane = threadIdx.x & 63;
    int f = lane & 7;
    int g = lane >> 3;
    if (gw >= N_NODES) return;
    int beg = rowptr[gw], end = rowptr[gw + 1];
    const uint4* h16 = (const uint4*)hplane;

    float a[8] = {0.f, 0.f, 0.f, 0.f, 0.f, 0.f, 0.f, 0.f};
    float b[8] = {0.f, 0.f, 0.f, 0.f, 0.f, 0.f, 0.f, 0.f};
    int p = beg + g;
    for (; p + 8 < end; p += 16) {
        int s0 = col[p], s1 = col[p + 8];
        uint4 v0 = h16[s0 * 8 + f];
        uint4 v1 = h16[s1 * 8 + f];
        acc8(a, v0);
        acc8(b, v1);
    }
    if (p < end) {
        uint4 v = h16[col[p] * 8 + f];
        acc8(a, v);
    }
#pragma unroll
    for (int j = 0; j < 8; ++j) {
        float v = a[j] + b[j];
        v += __shfl_xor(v, 8);
        v += __shfl_xor(v, 16);
        v += __shfl_xor(v, 32);
        a[j] = v;
    }
    if (g == 0) {
        float inv = 1.0f / fmaxf((float)(end - beg), 1.0f);
        unsigned hws[4], lws[4];
#pragma unroll
        for (int i = 0; i < 4; ++i) {
            float v0 = a[2 * i] * inv, v1 = a[2 * i + 1] * inv;
            unsigned short h0 = bf16rne(v0), h1 = bf16rne(v1);
            hws[i] = (unsigned)h0 | ((unsigned)h1 << 16);
            lws[i] = (unsigned)bf16rne(v0 - bf2f(h0)) |
                     ((unsigned)bf16rne(v1 - bf2f(h1)) << 16);
        }
        uint4 hv = {hws[0], hws[1], hws[2], hws[3]};
        uint4 lv = {lws[0], lws[1], lws[2], lws[3]};
        ((uint4*)mh)[gw * 8 + f] = hv;
        ((uint4*)ml)[gw * 8 + f] = lv;
    }
}

// ---- per-tile matmul: one wave per 16 nodes; no atomics. ----
template <int XMODE>
__global__ __launch_bounds__(64) void mm_kernel(
    const float* __restrict__ xf, const ushort_t* __restrict__ xhp,
    const ushort_t* __restrict__ mh, const ushort_t* __restrict__ ml,
    const short* __restrict__ wl, const short* __restrict__ wr, const short* __restrict__ wm,
    const float* __restrict__ blv, const float* __restrict__ bmv,
    ushort_t* __restrict__ hhout) {
    __shared__ short smh[16 * TPAD];
    __shared__ short sml[16 * TPAD];
    __shared__ short sxh[16 * TPAD];
    __shared__ short sxl[16 * TPAD];
    __shared__ short sth[16 * TPAD];
    __shared__ short stl[16 * TPAD];

    int lane = threadIdx.x;
    int f = lane & 15;
    int g = lane >> 4;
    int base = blockIdx.x * 16;

    {
        const uint4* mh16 = (const uint4*)mh;
        const uint4* ml16 = (const uint4*)ml;
#pragma unroll
        for (int i = 0; i < 2; ++i) {
            int c = i * 64 + lane;
            int r = c >> 3, cc = c & 7;
            *(uint4*)&smh[r * TPAD + cc * 8] = mh16[(base + r) * 8 + cc];
            *(uint4*)&sml[r * TPAD + cc * 8] = ml16[(base + r) * 8 + cc];
        }
    }
    if (XMODE == 1) {
        const uint4* xh16 = (const uint4*)xhp;
#pragma unroll
        for (int i = 0; i < 2; ++i) {
            int c = i * 64 + lane;
            int r = c >> 3, cc = c & 7;
            *(uint4*)&sxh[r * TPAD + cc * 8] = xh16[(base + r) * 8 + cc];
        }
    } else {
        const float4* x4 = (const float4*)xf;
#pragma unroll
        for (int i = 0; i < 4; ++i) {
            int idx = i * 64 + lane;
            int r = idx >> 4, c = idx & 15;
            float4 xv = x4[(size_t)(base + r) * 16 + c];
            unsigned short h0 = bf16rne(xv.x), h1 = bf16rne(xv.y),
                           h2 = bf16rne(xv.z), h3 = bf16rne(xv.w);
            uint2 hw, lw;
            hw.x = (unsigned)h0 | ((unsigned)h1 << 16);
            hw.y = (unsigned)h2 | ((unsigned)h3 << 16);
            lw.x = (unsigned)bf16rne(xv.x - bf2f(h0)) | ((unsigned)bf16rne(xv.y - bf2f(h1)) << 16);
            lw.y = (unsigned)bf16rne(xv.z - bf2f(h2)) | ((unsigned)bf16rne(xv.w - bf2f(h3)) << 16);
            *(uint2*)&sxh[r * TPAD + c * 4] = hw;
            *(uint2*)&sxl[r * TPAD + c * 4] = lw;
        }
    }

    short8 amh[2], aml[2], axh[2], axl[2];
#pragma unroll
    for (int kt = 0; kt < 2; ++kt) {
        int idx = f * TPAD + kt * 32 + g * 8;
        amh[kt] = *(const short8*)&smh[idx];
        aml[kt] = *(const short8*)&sml[idx];
        axh[kt] = *(const short8*)&sxh[idx];
        if (XMODE == 0) axl[kt] = *(const short8*)&sxl[idx];
    }
    const short* wlh = wl;
    const short* wll = wl + 4096;
    const short* wrh = wr;
    const short* wrl = wr + 4096;

#pragma unroll
    for (int nt = 0; nt < 4; ++nt) {
        f32x4 acc = {0.f, 0.f, 0.f, 0.f};
#pragma unroll
        for (int kt = 0; kt < 2; ++kt) {
            int fi = ((kt * 4 + nt) * 64 + lane) * 8;
            short8 blh = *(const short8*)&wlh[fi];
            short8 bll = *(const short8*)&wll[fi];
            short8 brh = *(const short8*)&wrh[fi];
            short8 brl = *(const short8*)&wrl[fi];
            acc = MFMA16(amh[kt], blh, acc);
            acc = MFMA16(aml[kt], blh, acc);
            acc = MFMA16(amh[kt], bll, acc);
            acc = MFMA16(axh[kt], brh, acc);
            if (XMODE == 0) acc = MFMA16(axl[kt], brh, acc);
            acc = MFMA16(axh[kt], brl, acc);
        }
        float bias = blv[nt * 16 + f];
#pragma unroll
        for (int r = 0; r < 4; ++r) {
            float tv = acc[r] + bias;
            unsigned short hi = bf16rne(tv);
            unsigned short lo = bf16rne(tv - bf2f(hi));
            int row = g * 4 + r;
            sth[row * TPAD + nt * 16 + f] = (short)hi;
            stl[row * TPAD + nt * 16 + f] = (short)lo;
        }
    }

    short8 ath[2], atl[2];
#pragma unroll
    for (int kt = 0; kt < 2; ++kt) {
        int idx = f * TPAD + kt * 32 + g * 8;
        ath[kt] = *(const short8*)&sth[idx];
        atl[kt] = *(const short8*)&stl[idx];
    }
    const short* wmh = wm;
    const short* wml = wm + 4096;
#pragma unroll
    for (int nt = 0; nt < 4; ++nt) {
        f32x4 acc = {0.f, 0.f, 0.f, 0.f};
#pragma unroll
        for (int kt = 0; kt < 2; ++kt) {
            int fi = ((kt * 4 + nt) * 64 + lane) * 8;
            short8 bh  = *(const short8*)&wmh[fi];
            short8 bl2 = *(const short8*)&wml[fi];
            acc = MFMA16(ath[kt], bh, acc);
            acc = MFMA16(atl[kt], bh, acc);
            acc = MFMA16(ath[kt], bl2, acc);
        }
        float bias = bmv[nt * 16 + f];
#pragma unroll
        for (int r = 0; r < 4; ++r) {
            float hv = acc[r] + bias;
            hv = hv > 0.f ? hv : 0.f;
            int row  = g * 4 + r;
            int node = base + row;
            hhout[node * D + nt * 16 + f] = bf16rne(hv);
        }
    }
}

// ---- fused segmented mean-pool + MLP over bf16 h planes ----
__global__ __launch_bounds__(256) void poolmlp_kernel(
    const ushort_t* __restrict__ h0, const ushort_t* __restrict__ h1,
    const ushort_t* __restrict__ h2, const int* __restrict__ gstart,
    const float* __restrict__ W1, const float* __restrict__ b1,
    const float* __restrict__ W2, const float* __restrict__ b2,
    float* __restrict__ out) {
    __shared__ float spart[4][3][64];
    __shared__ float sg[3 * 64];
    __shared__ float tt[64];
    int gr = blockIdx.x;
    int w = threadIdx.x >> 6, lane = threadIdx.x & 63;
    int beg = gstart[gr], end = gstart[gr + 1];
    float s0 = 0.f, s1 = 0.f, s2 = 0.f;
    for (int n = beg + w; n < end; n += 4) {
        s0 += bf2f(h0[n * 64 + lane]);
        s1 += bf2f(h1[n * 64 + lane]);
        s2 += bf2f(h2[n * 64 + lane]);
    }
    spart[w][0][lane] = s0; spart[w][1][lane] = s1; spart[w][2][lane] = s2;
    __syncthreads();
    if (w == 0) {
        float inv = 1.0f / fmaxf((float)(end - beg), 1.0f);
#pragma unroll
        for (int l = 0; l < 3; ++l)
            sg[l * 64 + lane] = (spart[0][l][lane] + spart[1][l][lane] +
                                 spart[2][l][lane] + spart[3][l][lane]) * inv;
    }
    __syncthreads();
    if (w == 0) {
        float acc = b1[lane];
#pragma unroll 8
        for (int k = 0; k < 3 * 64; ++k) acc += sg[k] * W1[k * 64 + lane];
        tt[lane] = fmaxf(acc, 0.f);
    }
    __syncthreads();
    if (w == 0 && lane < D_TARGET) {
        float acc = b2[lane];
#pragma unroll
        for (int k = 0; k < 64; ++k) acc += tt[k] * W2[k * D_TARGET + lane];
        out[gr * D_TARGET + lane] = acc;
    }
}

extern "C" void kernel_launch(void* const* d_in, const int* in_sizes, int n_in,
                              void* d_out, int out_size, void* d_ws, size_t ws_size,
                              hipStream_t stream) {
    const float* x     = (const float*)d_in[0];
    const int*   ei    = (const int*)d_in[1];
    const int*   src   = ei;
    const int*   dst   = ei + N_EDGES;
    const int*   batch = (const int*)d_in[2];

    const float* Wl[3] = {(const float*)d_in[3], (const float*)d_in[6], (const float*)d_in[9]};
    const float* bl[3] = {(const float*)d_in[4], (const float*)d_in[7], (const float*)d_in[10]};
    const float* Wr[3] = {(const float*)d_in[5], (const float*)d_in[8], (const float*)d_in[11]};
    const float* Wm = (const float*)d_in[12];
    const float* bm = (const float*)d_in[13];
    const float* W1 = (const float*)d_in[14];
    const float* b1 = (const float*)d_in[15];
    const float* W2 = (const float*)d_in[16];
    const float* b2 = (const float*)d_in[17];

    // workspace layout (4-byte words; sections 16B-aligned)
    int*      degi    = (int*)d_ws;                       // 50000
    int*      partial = degi + 50000;                     // 256
    int*      rowptr  = partial + 256;                    // 50001 -> pad 50008
    int*      next    = rowptr + 50008;                   // 50000
    int*      gstart  = next + 50000;                     // 513 -> pad 520
    short*    wfrag   = (short*)(gstart + 520);           // 7*8192 shorts
    ushort_t* col     = (ushort_t*)(wfrag + 7 * 8192);    // 800000 ushort
    ushort_t* xh      = col + 800000;                     // 3.2M ushort
    ushort_t* mh      = xh + (size_t)N_NODES * D;
    ushort_t* ml      = mh + (size_t)N_NODES * D;
    ushort_t* hh0     = ml + (size_t)N_NODES * D;
    ushort_t* hh1     = hh0 + (size_t)N_NODES * D;
    ushort_t* hh2     = hh1 + (size_t)N_NODES * D;

    hipMemsetAsync(degi, 0, 50000 * sizeof(int), stream);

    k1_kernel<<<EDGE_BLOCKS + NB_SCAN, 256, 0, stream>>>(dst, batch, degi, gstart);
    scan_partials<<<NB_SCAN, 256, 0, stream>>>(degi, partial);
    scan_final<<<NB_SCAN, 256, 0, stream>>>(degi, partial, rowptr, next);
    k4_kernel<<<FILL_BLOCKS + XSPLIT_BLOCKS + WPREP_BLOCKS, 256, 0, stream>>>(
        src, dst, next, col, x, xh,
        Wl[0], Wr[0], Wl[1], Wr[1], Wl[2], Wr[2], Wm, wfrag);

    ushort_t* hplanes[4] = {xh, hh0, hh1, hh2};
    for (int l = 0; l < 3; ++l) {
        gather_kernel<<<(N_NODES * 64 + 511) / 512, 512, 0, stream>>>(
            hplanes[l], rowptr, col, mh, ml);
        if (l == 0)
            mm_kernel<0><<<N_NODES / 16, 64, 0, stream>>>(
                x, nullptr, mh, ml,
                wfrag + 0 * 8192, wfrag + 1 * 8192, wfrag + 6 * 8192,
                bl[0], bm, hh0);
        else
            mm_kernel<1><<<N_NODES / 16, 64, 0, stream>>>(
                nullptr, hplanes[l], mh, ml,
                wfrag + (2 * l) * 8192, wfrag + (2 * l + 1) * 8192, wfrag + 6 * 8192,
                bl[l], bm, hplanes[l + 1]);
    }

    poolmlp_kernel<<<N_GRAPHS, 256, 0, stream>>>(hh0, hh1, hh2, gstart, W1, b1, W2, b2,
                                                 (float*)d_out);
}

// Round 12
// 208.137 us; speedup vs baseline: 2.3289x; 1.0300x over previous
//
#include <hip/hip_runtime.h>

// GraphSAGE forward: bf16-plane storage, uint16 CSR col, XCD-swizzled binned fill,
// fused small kernels, atomic-free pooling, bf16x3-split MFMA matmuls.
#define N_NODES 50000
#define N_EDGES 800000
#define D 64
#define N_GRAPHS 512
#define D_TARGET 10
#define NB_SCAN ((N_NODES + 255) / 256)   // 196
#define TPAD 72                            // LDS tile row stride in bf16
#define NBIN 8
#define NODES_PER_BIN (N_NODES / NBIN)     // 6250
#define EDGE_BLOCKS (N_EDGES / 256)        // 3125 (exact)
#define FILL_BLOCKS (NBIN * EDGE_BLOCKS)   // 25000
#define XSPLIT_BLOCKS EDGE_BLOCKS          // 3125
#define WPREP_BLOCKS 112                   // 7*4096/256

typedef __attribute__((ext_vector_type(8))) short short8;
typedef __attribute__((ext_vector_type(4))) float f32x4;
typedef unsigned short ushort_t;
#define MFMA16(a, b, c) __builtin_amdgcn_mfma_f32_16x16x32_bf16(a, b, c, 0, 0, 0)

__device__ inline unsigned short bf16rne(float f) {
    unsigned u = __builtin_bit_cast(unsigned, f);
    u += 0x7FFFu + ((u >> 16) & 1u);
    return (unsigned short)(u >> 16);
}
__device__ inline float bf2f(unsigned short h) {
    unsigned u = ((unsigned)h) << 16;
    return __builtin_bit_cast(float, u);
}
__device__ inline void acc8(float* a, uint4 v) {
    a[0] += __builtin_bit_cast(float, v.x << 16);
    a[1] += __builtin_bit_cast(float, v.x & 0xFFFF0000u);
    a[2] += __builtin_bit_cast(float, v.y << 16);
    a[3] += __builtin_bit_cast(float, v.y & 0xFFFF0000u);
    a[4] += __builtin_bit_cast(float, v.z << 16);
    a[5] += __builtin_bit_cast(float, v.z & 0xFFFF0000u);
    a[6] += __builtin_bit_cast(float, v.w << 16);
    a[7] += __builtin_bit_cast(float, v.w & 0xFFFF0000u);
}

// ---- K1: degree histogram (no-return atomics, fast) + graph ranges ----
__global__ void k1_kernel(const int* __restrict__ dst, const int* __restrict__ batch,
                          int* __restrict__ degi, int* __restrict__ gstart) {
    int b = blockIdx.x;
    if (b < EDGE_BLOCKS) {
        int e = b * 256 + threadIdx.x;   // exact, no guard
        atomicAdd(&degi[dst[e]], 1);
    } else {
        int i = (b - EDGE_BLOCKS) * 256 + threadIdx.x;
        if (i >= N_NODES) return;
        int bb = batch[i];
        int prev = (i == 0) ? -1 : batch[i - 1];
        for (int g = prev + 1; g <= bb; ++g) gstart[g] = i;
        if (i == N_NODES - 1)
            for (int g = bb + 1; g <= N_GRAPHS; ++g) gstart[g] = N_NODES;
    }
}

// ---- K2: per-256-chunk sums ----
__global__ void scan_partials(const int* __restrict__ degi, int* __restrict__ partial) {
    __shared__ int s[256];
    int t = threadIdx.x;
    int i = blockIdx.x * 256 + t;
    s[t] = (i < N_NODES) ? degi[i] : 0;
    __syncthreads();
    for (int off = 128; off > 0; off >>= 1) {
        if (t < off) s[t] += s[t + off];
        __syncthreads();
    }
    if (t == 0) partial[blockIdx.x] = s[0];
}

// ---- K3: per-chunk inclusive scan with inline partial-prefix reduction ----
__global__ void scan_final(const int* __restrict__ degi, const int* __restrict__ partial,
                           int* __restrict__ rowptr, int* __restrict__ next) {
    __shared__ int s[256];
    __shared__ int sp[256];
    int t = threadIdx.x;
    int i = blockIdx.x * 256 + t;
    sp[t] = (t < blockIdx.x) ? partial[t] : 0;   // blockIdx.x <= 195 < 256
    __syncthreads();
    for (int off = 128; off > 0; off >>= 1) {
        if (t < off) sp[t] += sp[t + off];
        __syncthreads();
    }
    int prefix = sp[0];
    int v = (i < N_NODES) ? degi[i] : 0;
    s[t] = v;
    __syncthreads();
    for (int off = 1; off < 256; off <<= 1) {
        int add = (t >= off) ? s[t - off] : 0;
        __syncthreads();
        s[t] += add;
        __syncthreads();
    }
    if (i < N_NODES) {
        int excl = prefix + s[t] - v;
        rowptr[i] = excl;
        next[i]   = excl;
    }
    if (i == 0) rowptr[N_NODES] = N_EDGES;
}

// ---- K4: XCD-swizzled binned CSR fill + x->bf16 + weight prep ----
// bin = blockIdx % 8: consecutive blocks round-robin across XCDs, so each bin's
// next[]-window + col[]-window stay resident in ONE XCD's L2 (atomic locality).
__global__ void k4_kernel(const int* __restrict__ src, const int* __restrict__ dst,
                          int* __restrict__ next, ushort_t* __restrict__ col,
                          const float* __restrict__ x, ushort_t* __restrict__ xh,
                          const float* __restrict__ w0, const float* __restrict__ w1,
                          const float* __restrict__ w2, const float* __restrict__ w3,
                          const float* __restrict__ w4, const float* __restrict__ w5,
                          const float* __restrict__ w6, short* __restrict__ wfrag) {
    int b = blockIdx.x;
    if (b < FILL_BLOCKS) {
        int bin   = b & (NBIN - 1);       // XCD-aligned
        int chunk = b >> 3;               // 0..3124
        int e = chunk * 256 + threadIdx.x;   // exact
        int d = dst[e];
        int lo = bin * NODES_PER_BIN;
        if (d >= lo && d < lo + NODES_PER_BIN) {
            int pos = atomicAdd(&next[d], 1);
            col[pos] = (ushort_t)src[e];
        }
    } else if (b < FILL_BLOCKS + XSPLIT_BLOCKS) {
        int idx = (b - FILL_BLOCKS) * 256 + threadIdx.x;   // float4 index, exact
        float4 v = ((const float4*)x)[idx];
        ushort4 o;
        o.x = bf16rne(v.x); o.y = bf16rne(v.y); o.z = bf16rne(v.z); o.w = bf16rne(v.w);
        ((ushort4*)xh)[idx] = o;
    } else {
        int tid = (b - FILL_BLOCKS - XSPLIT_BLOCKS) * 256 + threadIdx.x;  // 0..7*4096-1
        int m = tid >> 12, t = tid & 4095;
        const float* W = (m == 0) ? w0 : (m == 1) ? w1 : (m == 2) ? w2 : (m == 3) ? w3
                       : (m == 4) ? w4 : (m == 5) ? w5 : w6;
        int j = t & 7, lane = (t >> 3) & 63, nt = (t >> 9) & 3, kt = t >> 11;
        int k = kt * 32 + ((lane >> 4) << 3) + j;
        int o = nt * 16 + (lane & 15);
        float v = W[k * 64 + o];
        unsigned short hi = bf16rne(v);
        unsigned short lo = bf16rne(v - bf2f(hi));
        wfrag[m * 8192 + t]        = (short)hi;
        wfrag[m * 8192 + 4096 + t] = (short)lo;
    }
}

// ---- pure gather over bf16 plane: one wave per node; 8 subgroups x 8 lanes ----
__global__ __launch_bounds__(512) void gather_kernel(
    const ushort_t* __restrict__ hplane, const int* __restrict__ rowptr,
    const ushort_t* __restrict__ col,
    ushort_t* __restrict__ mh, ushort_t* __restrict__ ml) {
    int gw   = (blockIdx.x * 512 + threadIdx.x) >> 6;   // node
    int lane = threadIdx.x & 63;
    int f = lane & 7;
    int g = lane >> 3;
    if (gw >= N_NODES) return;
    int beg = rowptr[gw], end = rowptr[gw + 1];
    const uint4* h16 = (const uint4*)hplane;

    float a[8] = {0.f, 0.f, 0.f, 0.f, 0.f, 0.f, 0.f, 0.f};
    float b[8] = {0.f, 0.f, 0.f, 0.f, 0.f, 0.f, 0.f, 0.f};
    int p = beg + g;
    for (; p + 8 < end; p += 16) {
        int s0 = col[p], s1 = col[p + 8];
        uint4 v0 = h16[s0 * 8 + f];
        uint4 v1 = h16[s1 * 8 + f];
        acc8(a, v0);
        acc8(b, v1);
    }
    if (p < end) {
        uint4 v = h16[col[p] * 8 + f];
        acc8(a, v);
    }
#pragma unroll
    for (int j = 0; j < 8; ++j) {
        float v = a[j] + b[j];
        v += __shfl_xor(v, 8);
        v += __shfl_xor(v, 16);
        v += __shfl_xor(v, 32);
        a[j] = v;
    }
    if (g == 0) {
        float inv = 1.0f / fmaxf((float)(end - beg), 1.0f);
        unsigned hws[4], lws[4];
#pragma unroll
        for (int i = 0; i < 4; ++i) {
            float v0 = a[2 * i] * inv, v1 = a[2 * i + 1] * inv;
            unsigned short h0 = bf16rne(v0), h1 = bf16rne(v1);
            hws[i] = (unsigned)h0 | ((unsigned)h1 << 16);
            lws[i] = (unsigned)bf16rne(v0 - bf2f(h0)) |
                     ((unsigned)bf16rne(v1 - bf2f(h1)) << 16);
        }
        uint4 hv = {hws[0], hws[1], hws[2], hws[3]};
        uint4 lv = {lws[0], lws[1], lws[2], lws[3]};
        ((uint4*)mh)[gw * 8 + f] = hv;
        ((uint4*)ml)[gw * 8 + f] = lv;
    }
}

// ---- per-tile matmul: one wave per 16 nodes; no atomics. ----
template <int XMODE>
__global__ __launch_bounds__(64) void mm_kernel(
    const float* __restrict__ xf, const ushort_t* __restrict__ xhp,
    const ushort_t* __restrict__ mh, const ushort_t* __restrict__ ml,
    const short* __restrict__ wl, const short* __restrict__ wr, const short* __restrict__ wm,
    const float* __restrict__ blv, const float* __restrict__ bmv,
    ushort_t* __restrict__ hhout) {
    __shared__ short smh[16 * TPAD];
    __shared__ short sml[16 * TPAD];
    __shared__ short sxh[16 * TPAD];
    __shared__ short sxl[16 * TPAD];
    __shared__ short sth[16 * TPAD];
    __shared__ short stl[16 * TPAD];

    int lane = threadIdx.x;
    int f = lane & 15;
    int g = lane >> 4;
    int base = blockIdx.x * 16;

    {
        const uint4* mh16 = (const uint4*)mh;
        const uint4* ml16 = (const uint4*)ml;
#pragma unroll
        for (int i = 0; i < 2; ++i) {
            int c = i * 64 + lane;
            int r = c >> 3, cc = c & 7;
            *(uint4*)&smh[r * TPAD + cc * 8] = mh16[(base + r) * 8 + cc];
            *(uint4*)&sml[r * TPAD + cc * 8] = ml16[(base + r) * 8 + cc];
        }
    }
    if (XMODE == 1) {
        const uint4* xh16 = (const uint4*)xhp;
#pragma unroll
        for (int i = 0; i < 2; ++i) {
            int c = i * 64 + lane;
            int r = c >> 3, cc = c & 7;
            *(uint4*)&sxh[r * TPAD + cc * 8] = xh16[(base + r) * 8 + cc];
        }
    } else {
        const float4* x4 = (const float4*)xf;
#pragma unroll
        for (int i = 0; i < 4; ++i) {
            int idx = i * 64 + lane;
            int r = idx >> 4, c = idx & 15;
            float4 xv = x4[(size_t)(base + r) * 16 + c];
            unsigned short h0 = bf16rne(xv.x), h1 = bf16rne(xv.y),
                           h2 = bf16rne(xv.z), h3 = bf16rne(xv.w);
            uint2 hw, lw;
            hw.x = (unsigned)h0 | ((unsigned)h1 << 16);
            hw.y = (unsigned)h2 | ((unsigned)h3 << 16);
            lw.x = (unsigned)bf16rne(xv.x - bf2f(h0)) | ((unsigned)bf16rne(xv.y - bf2f(h1)) << 16);
            lw.y = (unsigned)bf16rne(xv.z - bf2f(h2)) | ((unsigned)bf16rne(xv.w - bf2f(h3)) << 16);
            *(uint2*)&sxh[r * TPAD + c * 4] = hw;
            *(uint2*)&sxl[r * TPAD + c * 4] = lw;
        }
    }

    short8 amh[2], aml[2], axh[2], axl[2];
#pragma unroll
    for (int kt = 0; kt < 2; ++kt) {
        int idx = f * TPAD + kt * 32 + g * 8;
        amh[kt] = *(const short8*)&smh[idx];
        aml[kt] = *(const short8*)&sml[idx];
        axh[kt] = *(const short8*)&sxh[idx];
        if (XMODE == 0) axl[kt] = *(const short8*)&sxl[idx];
    }
    const short* wlh = wl;
    const short* wll = wl + 4096;
    const short* wrh = wr;
    const short* wrl = wr + 4096;

#pragma unroll
    for (int nt = 0; nt < 4; ++nt) {
        f32x4 acc = {0.f, 0.f, 0.f, 0.f};
#pragma unroll
        for (int kt = 0; kt < 2; ++kt) {
            int fi = ((kt * 4 + nt) * 64 + lane) * 8;
            short8 blh = *(const short8*)&wlh[fi];
            short8 bll = *(const short8*)&wll[fi];
            short8 brh = *(const short8*)&wrh[fi];
            short8 brl = *(const short8*)&wrl[fi];
            acc = MFMA16(amh[kt], blh, acc);
            acc = MFMA16(aml[kt], blh, acc);
            acc = MFMA16(amh[kt], bll, acc);
            acc = MFMA16(axh[kt], brh, acc);
            if (XMODE == 0) acc = MFMA16(axl[kt], brh, acc);
            acc = MFMA16(axh[kt], brl, acc);
        }
        float bias = blv[nt * 16 + f];
#pragma unroll
        for (int r = 0; r < 4; ++r) {
            float tv = acc[r] + bias;
            unsigned short hi = bf16rne(tv);
            unsigned short lo = bf16rne(tv - bf2f(hi));
            int row = g * 4 + r;
            sth[row * TPAD + nt * 16 + f] = (short)hi;
            stl[row * TPAD + nt * 16 + f] = (short)lo;
        }
    }

    short8 ath[2], atl[2];
#pragma unroll
    for (int kt = 0; kt < 2; ++kt) {
        int idx = f * TPAD + kt * 32 + g * 8;
        ath[kt] = *(const short8*)&sth[idx];
        atl[kt] = *(const short8*)&stl[idx];
    }
    const short* wmh = wm;
    const short* wml = wm + 4096;
#pragma unroll
    for (int nt = 0; nt < 4; ++nt) {
        f32x4 acc = {0.f, 0.f, 0.f, 0.f};
#pragma unroll
        for (int kt = 0; kt < 2; ++kt) {
            int fi = ((kt * 4 + nt) * 64 + lane) * 8;
            short8 bh  = *(const short8*)&wmh[fi];
            short8 bl2 = *(const short8*)&wml[fi];
            acc = MFMA16(ath[kt], bh, acc);
            acc = MFMA16(atl[kt], bh, acc);
            acc = MFMA16(ath[kt], bl2, acc);
        }
        float bias = bmv[nt * 16 + f];
#pragma unroll
        for (int r = 0; r < 4; ++r) {
            float hv = acc[r] + bias;
            hv = hv > 0.f ? hv : 0.f;
            int row  = g * 4 + r;
            int node = base + row;
            hhout[node * D + nt * 16 + f] = bf16rne(hv);
        }
    }
}

// ---- fused segmented mean-pool + MLP over bf16 h planes ----
__global__ __launch_bounds__(256) void poolmlp_kernel(
    const ushort_t* __restrict__ h0, const ushort_t* __restrict__ h1,
    const ushort_t* __restrict__ h2, const int* __restrict__ gstart,
    const float* __restrict__ W1, const float* __restrict__ b1,
    const float* __restrict__ W2, const float* __restrict__ b2,
    float* __restrict__ out) {
    __shared__ float spart[4][3][64];
    __shared__ float sg[3 * 64];
    __shared__ float tt[64];
    int gr = blockIdx.x;
    int w = threadIdx.x >> 6, lane = threadIdx.x & 63;
    int beg = gstart[gr], end = gstart[gr + 1];
    float s0 = 0.f, s1 = 0.f, s2 = 0.f;
    for (int n = beg + w; n < end; n += 4) {
        s0 += bf2f(h0[n * 64 + lane]);
        s1 += bf2f(h1[n * 64 + lane]);
        s2 += bf2f(h2[n * 64 + lane]);
    }
    spart[w][0][lane] = s0; spart[w][1][lane] = s1; spart[w][2][lane] = s2;
    __syncthreads();
    if (w == 0) {
        float inv = 1.0f / fmaxf((float)(end - beg), 1.0f);
#pragma unroll
        for (int l = 0; l < 3; ++l)
            sg[l * 64 + lane] = (spart[0][l][lane] + spart[1][l][lane] +
                                 spart[2][l][lane] + spart[3][l][lane]) * inv;
    }
    __syncthreads();
    if (w == 0) {
        float acc = b1[lane];
#pragma unroll 8
        for (int k = 0; k < 3 * 64; ++k) acc += sg[k] * W1[k * 64 + lane];
        tt[lane] = fmaxf(acc, 0.f);
    }
    __syncthreads();
    if (w == 0 && lane < D_TARGET) {
        float acc = b2[lane];
#pragma unroll
        for (int k = 0; k < 64; ++k) acc += tt[k] * W2[k * D_TARGET + lane];
        out[gr * D_TARGET + lane] = acc;
    }
}

extern "C" void kernel_launch(void* const* d_in, const int* in_sizes, int n_in,
                              void* d_out, int out_size, void* d_ws, size_t ws_size,
                              hipStream_t stream) {
    const float* x     = (const float*)d_in[0];
    const int*   ei    = (const int*)d_in[1];
    const int*   src   = ei;
    const int*   dst   = ei + N_EDGES;
    const int*   batch = (const int*)d_in[2];

    const float* Wl[3] = {(const float*)d_in[3], (const float*)d_in[6], (const float*)d_in[9]};
    const float* bl[3] = {(const float*)d_in[4], (const float*)d_in[7], (const float*)d_in[10]};
    const float* Wr[3] = {(const float*)d_in[5], (const float*)d_in[8], (const float*)d_in[11]};
    const float* Wm = (const float*)d_in[12];
    const float* bm = (const float*)d_in[13];
    const float* W1 = (const float*)d_in[14];
    const float* b1 = (const float*)d_in[15];
    const float* W2 = (const float*)d_in[16];
    const float* b2 = (const float*)d_in[17];

    // workspace layout (4-byte words; sections 16B-aligned)
    int*      degi    = (int*)d_ws;                       // 50000
    int*      partial = degi + 50000;                     // 256
    int*      rowptr  = partial + 256;                    // 50001 -> pad 50008
    int*      next    = rowptr + 50008;                   // 50000
    int*      gstart  = next + 50000;                     // 513 -> pad 520
    short*    wfrag   = (short*)(gstart + 520);           // 7*8192 shorts
    ushort_t* col     = (ushort_t*)(wfrag + 7 * 8192);    // 800000 ushort
    ushort_t* xh      = col + 800000;                     // 3.2M ushort
    ushort_t* mh      = xh + (size_t)N_NODES * D;
    ushort_t* ml      = mh + (size_t)N_NODES * D;
    ushort_t* hh0     = ml + (size_t)N_NODES * D;
    ushort_t* hh1     = hh0 + (size_t)N_NODES * D;
    ushort_t* hh2     = hh1 + (size_t)N_NODES * D;

    hipMemsetAsync(degi, 0, 50000 * sizeof(int), stream);

    k1_kernel<<<EDGE_BLOCKS + NB_SCAN, 256, 0, stream>>>(dst, batch, degi, gstart);
    scan_partials<<<NB_SCAN, 256, 0, stream>>>(degi, partial);
    scan_final<<<NB_SCAN, 256, 0, stream>>>(degi, partial, rowptr, next);
    k4_kernel<<<FILL_BLOCKS + XSPLIT_BLOCKS + WPREP_BLOCKS, 256, 0, stream>>>(
        src, dst, next, col, x, xh,
        Wl[0], Wr[0], Wl[1], Wr[1], Wl[2], Wr[2], Wm, wfrag);

    ushort_t* hplanes[4] = {xh, hh0, hh1, hh2};
    for (int l = 0; l < 3; ++l) {
        gather_kernel<<<(N_NODES * 64 + 511) / 512, 512, 0, stream>>>(
            hplanes[l], rowptr, col, mh, ml);
        if (l == 0)
            mm_kernel<0><<<N_NODES / 16, 64, 0, stream>>>(
                x, nullptr, mh, ml,
                wfrag + 0 * 8192, wfrag + 1 * 8192, wfrag + 6 * 8192,
                bl[0], bm, hh0);
        else
            mm_kernel<1><<<N_NODES / 16, 64, 0, stream>>>(
                nullptr, hplanes[l], mh, ml,
                wfrag + (2 * l) * 8192, wfrag + (2 * l + 1) * 8192, wfrag + 6 * 8192,
                bl[l], bm, hplanes[l + 1]);
    }

    poolmlp_kernel<<<N_GRAPHS, 256, 0, stream>>>(hh0, hh1, hh2, gstart, W1, b1, W2, b2,
                                                 (float*)d_out);
}

// Round 13
// 207.768 us; speedup vs baseline: 2.3331x; 1.0018x over previous
//
#include <hip/hip_runtime.h>

// GraphSAGE forward: bf16-plane storage, uint16 CSR col, XCD-swizzled binned fill,
// fused small kernels, atomic-free pooling, bf16x3-split MFMA matmuls.
// R13: replace hipMemsetAsync(degi) (43us rocclr fillBuffer!) with a plain zero kernel.
#define N_NODES 50000
#define N_EDGES 800000
#define D 64
#define N_GRAPHS 512
#define D_TARGET 10
#define NB_SCAN ((N_NODES + 255) / 256)   // 196
#define TPAD 72                            // LDS tile row stride in bf16
#define NBIN 8
#define NODES_PER_BIN (N_NODES / NBIN)     // 6250
#define EDGE_BLOCKS (N_EDGES / 256)        // 3125 (exact)
#define FILL_BLOCKS (NBIN * EDGE_BLOCKS)   // 25000
#define XSPLIT_BLOCKS EDGE_BLOCKS          // 3125
#define WPREP_BLOCKS 112                   // 7*4096/256

typedef __attribute__((ext_vector_type(8))) short short8;
typedef __attribute__((ext_vector_type(4))) float f32x4;
typedef unsigned short ushort_t;
#define MFMA16(a, b, c) __builtin_amdgcn_mfma_f32_16x16x32_bf16(a, b, c, 0, 0, 0)

__device__ inline unsigned short bf16rne(float f) {
    unsigned u = __builtin_bit_cast(unsigned, f);
    u += 0x7FFFu + ((u >> 16) & 1u);
    return (unsigned short)(u >> 16);
}
__device__ inline float bf2f(unsigned short h) {
    unsigned u = ((unsigned)h) << 16;
    return __builtin_bit_cast(float, u);
}
__device__ inline void acc8(float* a, uint4 v) {
    a[0] += __builtin_bit_cast(float, v.x << 16);
    a[1] += __builtin_bit_cast(float, v.x & 0xFFFF0000u);
    a[2] += __builtin_bit_cast(float, v.y << 16);
    a[3] += __builtin_bit_cast(float, v.y & 0xFFFF0000u);
    a[4] += __builtin_bit_cast(float, v.z << 16);
    a[5] += __builtin_bit_cast(float, v.z & 0xFFFF0000u);
    a[6] += __builtin_bit_cast(float, v.w << 16);
    a[7] += __builtin_bit_cast(float, v.w & 0xFFFF0000u);
}

// ---- K0: zero the degree array (replaces 43us rocclr fillBuffer) ----
__global__ void zero_kernel(int* __restrict__ degi) {
    int i = blockIdx.x * 256 + threadIdx.x;
    if (i < N_NODES) degi[i] = 0;
}

// ---- K1: degree histogram (no-return atomics) + graph ranges ----
__global__ void k1_kernel(const int* __restrict__ dst, const int* __restrict__ batch,
                          int* __restrict__ degi, int* __restrict__ gstart) {
    int b = blockIdx.x;
    if (b < EDGE_BLOCKS) {
        int e = b * 256 + threadIdx.x;   // exact, no guard
        atomicAdd(&degi[dst[e]], 1);
    } else {
        int i = (b - EDGE_BLOCKS) * 256 + threadIdx.x;
        if (i >= N_NODES) return;
        int bb = batch[i];
        int prev = (i == 0) ? -1 : batch[i - 1];
        for (int g = prev + 1; g <= bb; ++g) gstart[g] = i;
        if (i == N_NODES - 1)
            for (int g = bb + 1; g <= N_GRAPHS; ++g) gstart[g] = N_NODES;
    }
}

// ---- K2: per-256-chunk sums ----
__global__ void scan_partials(const int* __restrict__ degi, int* __restrict__ partial) {
    __shared__ int s[256];
    int t = threadIdx.x;
    int i = blockIdx.x * 256 + t;
    s[t] = (i < N_NODES) ? degi[i] : 0;
    __syncthreads();
    for (int off = 128; off > 0; off >>= 1) {
        if (t < off) s[t] += s[t + off];
        __syncthreads();
    }
    if (t == 0) partial[blockIdx.x] = s[0];
}

// ---- K3: per-chunk inclusive scan with inline partial-prefix reduction ----
__global__ void scan_final(const int* __restrict__ degi, const int* __restrict__ partial,
                           int* __restrict__ rowptr, int* __restrict__ next) {
    __shared__ int s[256];
    __shared__ int sp[256];
    int t = threadIdx.x;
    int i = blockIdx.x * 256 + t;
    sp[t] = (t < blockIdx.x) ? partial[t] : 0;   // blockIdx.x <= 195 < 256
    __syncthreads();
    for (int off = 128; off > 0; off >>= 1) {
        if (t < off) sp[t] += sp[t + off];
        __syncthreads();
    }
    int prefix = sp[0];
    int v = (i < N_NODES) ? degi[i] : 0;
    s[t] = v;
    __syncthreads();
    for (int off = 1; off < 256; off <<= 1) {
        int add = (t >= off) ? s[t - off] : 0;
        __syncthreads();
        s[t] += add;
        __syncthreads();
    }
    if (i < N_NODES) {
        int excl = prefix + s[t] - v;
        rowptr[i] = excl;
        next[i]   = excl;
    }
    if (i == 0) rowptr[N_NODES] = N_EDGES;
}

// ---- K4: XCD-swizzled binned CSR fill + x->bf16 + weight prep ----
__global__ void k4_kernel(const int* __restrict__ src, const int* __restrict__ dst,
                          int* __restrict__ next, ushort_t* __restrict__ col,
                          const float* __restrict__ x, ushort_t* __restrict__ xh,
                          const float* __restrict__ w0, const float* __restrict__ w1,
                          const float* __restrict__ w2, const float* __restrict__ w3,
                          const float* __restrict__ w4, const float* __restrict__ w5,
                          const float* __restrict__ w6, short* __restrict__ wfrag) {
    int b = blockIdx.x;
    if (b < FILL_BLOCKS) {
        int bin   = b & (NBIN - 1);       // XCD-aligned
        int chunk = b >> 3;               // 0..3124
        int e = chunk * 256 + threadIdx.x;   // exact
        int d = dst[e];
        int lo = bin * NODES_PER_BIN;
        if (d >= lo && d < lo + NODES_PER_BIN) {
            int pos = atomicAdd(&next[d], 1);
            col[pos] = (ushort_t)src[e];
        }
    } else if (b < FILL_BLOCKS + XSPLIT_BLOCKS) {
        int idx = (b - FILL_BLOCKS) * 256 + threadIdx.x;   // float4 index, exact
        float4 v = ((const float4*)x)[idx];
        ushort4 o;
        o.x = bf16rne(v.x); o.y = bf16rne(v.y); o.z = bf16rne(v.z); o.w = bf16rne(v.w);
        ((ushort4*)xh)[idx] = o;
    } else {
        int tid = (b - FILL_BLOCKS - XSPLIT_BLOCKS) * 256 + threadIdx.x;  // 0..7*4096-1
        int m = tid >> 12, t = tid & 4095;
        const float* W = (m == 0) ? w0 : (m == 1) ? w1 : (m == 2) ? w2 : (m == 3) ? w3
                       : (m == 4) ? w4 : (m == 5) ? w5 : w6;
        int j = t & 7, lane = (t >> 3) & 63, nt = (t >> 9) & 3, kt = t >> 11;
        int k = kt * 32 + ((lane >> 4) << 3) + j;
        int o = nt * 16 + (lane & 15);
        float v = W[k * 64 + o];
        unsigned short hi = bf16rne(v);
        unsigned short lo = bf16rne(v - bf2f(hi));
        wfrag[m * 8192 + t]        = (short)hi;
        wfrag[m * 8192 + 4096 + t] = (short)lo;
    }
}

// ---- pure gather over bf16 plane: one wave per node; 8 subgroups x 8 lanes ----
__global__ __launch_bounds__(512) void gather_kernel(
    const ushort_t* __restrict__ hplane, const int* __restrict__ rowptr,
    const ushort_t* __restrict__ col,
    ushort_t* __restrict__ mh, ushort_t* __restrict__ ml) {
    int gw   = (blockIdx.x * 512 + threadIdx.x) >> 6;   // node
    int lane = threadIdx.x & 63;
    int f = lane & 7;
    int g = lane >> 3;
    if (gw >= N_NODES) return;
    int beg = rowptr[gw], end = rowptr[gw + 1];
    const uint4* h16 = (const uint4*)hplane;

    float a[8] = {0.f, 0.f, 0.f, 0.f, 0.f, 0.f, 0.f, 0.f};
    float b[8] = {0.f, 0.f, 0.f, 0.f, 0.f, 0.f, 0.f, 0.f};
    int p = beg + g;
    for (; p + 8 < end; p += 16) {
        int s0 = col[p], s1 = col[p + 8];
        uint4 v0 = h16[s0 * 8 + f];
        uint4 v1 = h16[s1 * 8 + f];
        acc8(a, v0);
        acc8(b, v1);
    }
    if (p < end) {
        uint4 v = h16[col[p] * 8 + f];
        acc8(a, v);
    }
#pragma unroll
    for (int j = 0; j < 8; ++j) {
        float v = a[j] + b[j];
        v += __shfl_xor(v, 8);
        v += __shfl_xor(v, 16);
        v += __shfl_xor(v, 32);
        a[j] = v;
    }
    if (g == 0) {
        float inv = 1.0f / fmaxf((float)(end - beg), 1.0f);
        unsigned hws[4], lws[4];
#pragma unroll
        for (int i = 0; i < 4; ++i) {
            float v0 = a[2 * i] * inv, v1 = a[2 * i + 1] * inv;
            unsigned short h0 = bf16rne(v0), h1 = bf16rne(v1);
            hws[i] = (unsigned)h0 | ((unsigned)h1 << 16);
            lws[i] = (unsigned)bf16rne(v0 - bf2f(h0)) |
                     ((unsigned)bf16rne(v1 - bf2f(h1)) << 16);
        }
        uint4 hv = {hws[0], hws[1], hws[2], hws[3]};
        uint4 lv = {lws[0], lws[1], lws[2], lws[3]};
        ((uint4*)mh)[gw * 8 + f] = hv;
        ((uint4*)ml)[gw * 8 + f] = lv;
    }
}

// ---- per-tile matmul: one wave per 16 nodes; no atomics. ----
template <int XMODE>
__global__ __launch_bounds__(64) void mm_kernel(
    const float* __restrict__ xf, const ushort_t* __restrict__ xhp,
    const ushort_t* __restrict__ mh, const ushort_t* __restrict__ ml,
    const short* __restrict__ wl, const short* __restrict__ wr, const short* __restrict__ wm,
    const float* __restrict__ blv, const float* __restrict__ bmv,
    ushort_t* __restrict__ hhout) {
    __shared__ short smh[16 * TPAD];
    __shared__ short sml[16 * TPAD];
    __shared__ short sxh[16 * TPAD];
    __shared__ short sxl[16 * TPAD];
    __shared__ short sth[16 * TPAD];
    __shared__ short stl[16 * TPAD];

    int lane = threadIdx.x;
    int f = lane & 15;
    int g = lane >> 4;
    int base = blockIdx.x * 16;

    {
        const uint4* mh16 = (const uint4*)mh;
        const uint4* ml16 = (const uint4*)ml;
#pragma unroll
        for (int i = 0; i < 2; ++i) {
            int c = i * 64 + lane;
            int r = c >> 3, cc = c & 7;
            *(uint4*)&smh[r * TPAD + cc * 8] = mh16[(base + r) * 8 + cc];
            *(uint4*)&sml[r * TPAD + cc * 8] = ml16[(base + r) * 8 + cc];
        }
    }
    if (XMODE == 1) {
        const uint4* xh16 = (const uint4*)xhp;
#pragma unroll
        for (int i = 0; i < 2; ++i) {
            int c = i * 64 + lane;
            int r = c >> 3, cc = c & 7;
            *(uint4*)&sxh[r * TPAD + cc * 8] = xh16[(base + r) * 8 + cc];
        }
    } else {
        const float4* x4 = (const float4*)xf;
#pragma unroll
        for (int i = 0; i < 4; ++i) {
            int idx = i * 64 + lane;
            int r = idx >> 4, c = idx & 15;
            float4 xv = x4[(size_t)(base + r) * 16 + c];
            unsigned short h0 = bf16rne(xv.x), h1 = bf16rne(xv.y),
                           h2 = bf16rne(xv.z), h3 = bf16rne(xv.w);
            uint2 hw, lw;
            hw.x = (unsigned)h0 | ((unsigned)h1 << 16);
            hw.y = (unsigned)h2 | ((unsigned)h3 << 16);
            lw.x = (unsigned)bf16rne(xv.x - bf2f(h0)) | ((unsigned)bf16rne(xv.y - bf2f(h1)) << 16);
            lw.y = (unsigned)bf16rne(xv.z - bf2f(h2)) | ((unsigned)bf16rne(xv.w - bf2f(h3)) << 16);
            *(uint2*)&sxh[r * TPAD + c * 4] = hw;
            *(uint2*)&sxl[r * TPAD + c * 4] = lw;
        }
    }

    short8 amh[2], aml[2], axh[2], axl[2];
#pragma unroll
    for (int kt = 0; kt < 2; ++kt) {
        int idx = f * TPAD + kt * 32 + g * 8;
        amh[kt] = *(const short8*)&smh[idx];
        aml[kt] = *(const short8*)&sml[idx];
        axh[kt] = *(const short8*)&sxh[idx];
        if (XMODE == 0) axl[kt] = *(const short8*)&sxl[idx];
    }
    const short* wlh = wl;
    const short* wll = wl + 4096;
    const short* wrh = wr;
    const short* wrl = wr + 4096;

#pragma unroll
    for (int nt = 0; nt < 4; ++nt) {
        f32x4 acc = {0.f, 0.f, 0.f, 0.f};
#pragma unroll
        for (int kt = 0; kt < 2; ++kt) {
            int fi = ((kt * 4 + nt) * 64 + lane) * 8;
            short8 blh = *(const short8*)&wlh[fi];
            short8 bll = *(const short8*)&wll[fi];
            short8 brh = *(const short8*)&wrh[fi];
            short8 brl = *(const short8*)&wrl[fi];
            acc = MFMA16(amh[kt], blh, acc);
            acc = MFMA16(aml[kt], blh, acc);
            acc = MFMA16(amh[kt], bll, acc);
            acc = MFMA16(axh[kt], brh, acc);
            if (XMODE == 0) acc = MFMA16(axl[kt], brh, acc);
            acc = MFMA16(axh[kt], brl, acc);
        }
        float bias = blv[nt * 16 + f];
#pragma unroll
        for (int r = 0; r < 4; ++r) {
            float tv = acc[r] + bias;
            unsigned short hi = bf16rne(tv);
            unsigned short lo = bf16rne(tv - bf2f(hi));
            int row = g * 4 + r;
            sth[row * TPAD + nt * 16 + f] = (short)hi;
            stl[row * TPAD + nt * 16 + f] = (short)lo;
        }
    }

    short8 ath[2], atl[2];
#pragma unroll
    for (int kt = 0; kt < 2; ++kt) {
        int idx = f * TPAD + kt * 32 + g * 8;
        ath[kt] = *(const short8*)&sth[idx];
        atl[kt] = *(const short8*)&stl[idx];
    }
    const short* wmh = wm;
    const short* wml = wm + 4096;
#pragma unroll
    for (int nt = 0; nt < 4; ++nt) {
        f32x4 acc = {0.f, 0.f, 0.f, 0.f};
#pragma unroll
        for (int kt = 0; kt < 2; ++kt) {
            int fi = ((kt * 4 + nt) * 64 + lane) * 8;
            short8 bh  = *(const short8*)&wmh[fi];
            short8 bl2 = *(const short8*)&wml[fi];
            acc = MFMA16(ath[kt], bh, acc);
            acc = MFMA16(atl[kt], bh, acc);
            acc = MFMA16(ath[kt], bl2, acc);
        }
        float bias = bmv[nt * 16 + f];
#pragma unroll
        for (int r = 0; r < 4; ++r) {
            float hv = acc[r] + bias;
            hv = hv > 0.f ? hv : 0.f;
            int row  = g * 4 + r;
            int node = base + row;
            hhout[node * D + nt * 16 + f] = bf16rne(hv);
        }
    }
}

// ---- fused segmented mean-pool + MLP over bf16 h planes ----
__global__ __launch_bounds__(256) void poolmlp_kernel(
    const ushort_t* __restrict__ h0, const ushort_t* __restrict__ h1,
    const ushort_t* __restrict__ h2, const int* __restrict__ gstart,
    const float* __restrict__ W1, const float* __restrict__ b1,
    const float* __restrict__ W2, const float* __restrict__ b2,
    float* __restrict__ out) {
    __shared__ float spart[4][3][64];
    __shared__ float sg[3 * 64];
    __shared__ float tt[64];
    int gr = blockIdx.x;
    int w = threadIdx.x >> 6, lane = threadIdx.x & 63;
    int beg = gstart[gr], end = gstart[gr + 1];
    float s0 = 0.f, s1 = 0.f, s2 = 0.f;
    for (int n = beg + w; n < end; n += 4) {
        s0 += bf2f(h0[n * 64 + lane]);
        s1 += bf2f(h1[n * 64 + lane]);
        s2 += bf2f(h2[n * 64 + lane]);
    }
    spart[w][0][lane] = s0; spart[w][1][lane] = s1; spart[w][2][lane] = s2;
    __syncthreads();
    if (w == 0) {
        float inv = 1.0f / fmaxf((float)(end - beg), 1.0f);
#pragma unroll
        for (int l = 0; l < 3; ++l)
            sg[l * 64 + lane] = (spart[0][l][lane] + spart[1][l][lane] +
                                 spart[2][l][lane] + spart[3][l][lane]) * inv;
    }
    __syncthreads();
    if (w == 0) {
        float acc = b1[lane];
#pragma unroll 8
        for (int k = 0; k < 3 * 64; ++k) acc += sg[k] * W1[k * 64 + lane];
        tt[lane] = fmaxf(acc, 0.f);
    }
    __syncthreads();
    if (w == 0 && lane < D_TARGET) {
        float acc = b2[lane];
#pragma unroll
        for (int k = 0; k < 64; ++k) acc += tt[k] * W2[k * D_TARGET + lane];
        out[gr * D_TARGET + lane] = acc;
    }
}

extern "C" void kernel_launch(void* const* d_in, const int* in_sizes, int n_in,
                              void* d_out, int out_size, void* d_ws, size_t ws_size,
                              hipStream_t stream) {
    const float* x     = (const float*)d_in[0];
    const int*   ei    = (const int*)d_in[1];
    const int*   src   = ei;
    const int*   dst   = ei + N_EDGES;
    const int*   batch = (const int*)d_in[2];

    const float* Wl[3] = {(const float*)d_in[3], (const float*)d_in[6], (const float*)d_in[9]};
    const float* bl[3] = {(const float*)d_in[4], (const float*)d_in[7], (const float*)d_in[10]};
    const float* Wr[3] = {(const float*)d_in[5], (const float*)d_in[8], (const float*)d_in[11]};
    const float* Wm = (const float*)d_in[12];
    const float* bm = (const float*)d_in[13];
    const float* W1 = (const float*)d_in[14];
    const float* b1 = (const float*)d_in[15];
    const float* W2 = (const float*)d_in[16];
    const float* b2 = (const float*)d_in[17];

    // workspace layout (4-byte words; sections 16B-aligned)
    int*      degi    = (int*)d_ws;                       // 50000
    int*      partial = degi + 50000;                     // 256
    int*      rowptr  = partial + 256;                    // 50001 -> pad 50008
    int*      next    = rowptr + 50008;                   // 50000
    int*      gstart  = next + 50000;                     // 513 -> pad 520
    short*    wfrag   = (short*)(gstart + 520);           // 7*8192 shorts
    ushort_t* col     = (ushort_t*)(wfrag + 7 * 8192);    // 800000 ushort
    ushort_t* xh      = col + 800000;                     // 3.2M ushort
    ushort_t* mh      = xh + (size_t)N_NODES * D;
    ushort_t* ml      = mh + (size_t)N_NODES * D;
    ushort_t* hh0     = ml + (size_t)N_NODES * D;
    ushort_t* hh1     = hh0 + (size_t)N_NODES * D;
    ushort_t* hh2     = hh1 + (size_t)N_NODES * D;

    zero_kernel<<<NB_SCAN, 256, 0, stream>>>(degi);

    k1_kernel<<<EDGE_BLOCKS + NB_SCAN, 256, 0, stream>>>(dst, batch, degi, gstart);
    scan_partials<<<NB_SCAN, 256, 0, stream>>>(degi, partial);
    scan_final<<<NB_SCAN, 256, 0, stream>>>(degi, partial, rowptr, next);
    k4_kernel<<<FILL_BLOCKS + XSPLIT_BLOCKS + WPREP_BLOCKS, 256, 0, stream>>>(
        src, dst, next, col, x, xh,
        Wl[0], Wr[0], Wl[1], Wr[1], Wl[2], Wr[2], Wm, wfrag);

    ushort_t* hplanes[4] = {xh, hh0, hh1, hh2};
    for (int l = 0; l < 3; ++l) {
        gather_kernel<<<(N_NODES * 64 + 511) / 512, 512, 0, stream>>>(
            hplanes[l], rowptr, col, mh, ml);
        if (l == 0)
            mm_kernel<0><<<N_NODES / 16, 64, 0, stream>>>(
                x, nullptr, mh, ml,
                wfrag + 0 * 8192, wfrag + 1 * 8192, wfrag + 6 * 8192,
                bl[0], bm, hh0);
        else
            mm_kernel<1><<<N_NODES / 16, 64, 0, stream>>>(
                nullptr, hplanes[l], mh, ml,
                wfrag + (2 * l) * 8192, wfrag + (2 * l + 1) * 8192, wfrag + 6 * 8192,
                bl[l], bm, hplanes[l + 1]);
    }

    poolmlp_kernel<<<N_GRAPHS, 256, 0, stream>>>(hh0, hh1, hh2, gstart, W1, b1, W2, b2,
                                                 (float*)d_out);
}

// Round 14
// 187.077 us; speedup vs baseline: 2.5911x; 1.1106x over previous
//
#include <hip/hip_runtime.h>

// GraphSAGE forward: bf16-plane storage, uint16 CSR col, RANK-BASED ATOMIC-FREE fill
// (rank captured from k1's histogram atomics), fused small kernels, atomic-free
// pooling, bf16x3-split MFMA matmuls.
#define N_NODES 50000
#define N_EDGES 800000
#define D 64
#define N_GRAPHS 512
#define D_TARGET 10
#define NB_SCAN ((N_NODES + 255) / 256)   // 196
#define TPAD 72                            // LDS tile row stride in bf16
#define EDGE_BLOCKS (N_EDGES / 256)        // 3125 (exact)
#define XSPLIT_BLOCKS EDGE_BLOCKS          // 3125
#define WPREP_BLOCKS 112                   // 7*4096/256

typedef __attribute__((ext_vector_type(8))) short short8;
typedef __attribute__((ext_vector_type(4))) float f32x4;
typedef unsigned short ushort_t;
#define MFMA16(a, b, c) __builtin_amdgcn_mfma_f32_16x16x32_bf16(a, b, c, 0, 0, 0)

__device__ inline unsigned short bf16rne(float f) {
    unsigned u = __builtin_bit_cast(unsigned, f);
    u += 0x7FFFu + ((u >> 16) & 1u);
    return (unsigned short)(u >> 16);
}
__device__ inline float bf2f(unsigned short h) {
    unsigned u = ((unsigned)h) << 16;
    return __builtin_bit_cast(float, u);
}
__device__ inline void acc8(float* a, uint4 v) {
    a[0] += __builtin_bit_cast(float, v.x << 16);
    a[1] += __builtin_bit_cast(float, v.x & 0xFFFF0000u);
    a[2] += __builtin_bit_cast(float, v.y << 16);
    a[3] += __builtin_bit_cast(float, v.y & 0xFFFF0000u);
    a[4] += __builtin_bit_cast(float, v.z << 16);
    a[5] += __builtin_bit_cast(float, v.z & 0xFFFF0000u);
    a[6] += __builtin_bit_cast(float, v.w << 16);
    a[7] += __builtin_bit_cast(float, v.w & 0xFFFF0000u);
}

// ---- K0: zero the degree array ----
__global__ void zero_kernel(int* __restrict__ degi) {
    int i = blockIdx.x * 256 + threadIdx.x;
    if (i < N_NODES) degi[i] = 0;
}

// ---- K1: degree histogram; the atomic RETURN is each edge's rank (kept!).
//      Also computes graph ranges from sorted batch. ----
__global__ void k1_kernel(const int* __restrict__ dst, const int* __restrict__ batch,
                          int* __restrict__ degi, int* __restrict__ rank,
                          int* __restrict__ gstart) {
    int b = blockIdx.x;
    if (b < EDGE_BLOCKS) {
        int e = b * 256 + threadIdx.x;   // exact, no guard
        rank[e] = atomicAdd(&degi[dst[e]], 1);
    } else {
        int i = (b - EDGE_BLOCKS) * 256 + threadIdx.x;
        if (i >= N_NODES) return;
        int bb = batch[i];
        int prev = (i == 0) ? -1 : batch[i - 1];
        for (int g = prev + 1; g <= bb; ++g) gstart[g] = i;
        if (i == N_NODES - 1)
            for (int g = bb + 1; g <= N_GRAPHS; ++g) gstart[g] = N_NODES;
    }
}

// ---- K2: per-256-chunk sums ----
__global__ void scan_partials(const int* __restrict__ degi, int* __restrict__ partial) {
    __shared__ int s[256];
    int t = threadIdx.x;
    int i = blockIdx.x * 256 + t;
    s[t] = (i < N_NODES) ? degi[i] : 0;
    __syncthreads();
    for (int off = 128; off > 0; off >>= 1) {
        if (t < off) s[t] += s[t + off];
        __syncthreads();
    }
    if (t == 0) partial[blockIdx.x] = s[0];
}

// ---- K3: per-chunk inclusive scan with inline partial-prefix reduction ----
__global__ void scan_final(const int* __restrict__ degi, const int* __restrict__ partial,
                           int* __restrict__ rowptr) {
    __shared__ int s[256];
    __shared__ int sp[256];
    int t = threadIdx.x;
    int i = blockIdx.x * 256 + t;
    sp[t] = (t < blockIdx.x) ? partial[t] : 0;   // blockIdx.x <= 195 < 256
    __syncthreads();
    for (int off = 128; off > 0; off >>= 1) {
        if (t < off) sp[t] += sp[t + off];
        __syncthreads();
    }
    int prefix = sp[0];
    int v = (i < N_NODES) ? degi[i] : 0;
    s[t] = v;
    __syncthreads();
    for (int off = 1; off < 256; off <<= 1) {
        int add = (t >= off) ? s[t - off] : 0;
        __syncthreads();
        s[t] += add;
        __syncthreads();
    }
    if (i < N_NODES) rowptr[i] = prefix + s[t] - v;
    if (i == 0) rowptr[N_NODES] = N_EDGES;
}

// ---- K4: single-pass ATOMIC-FREE CSR fill (pos = rowptr[dst]+rank) +
//      x->bf16 + weight prep, fused ----
__global__ void k4_kernel(const int* __restrict__ src, const int* __restrict__ dst,
                          const int* __restrict__ rank, const int* __restrict__ rowptr,
                          ushort_t* __restrict__ col,
                          const float* __restrict__ x, ushort_t* __restrict__ xh,
                          const float* __restrict__ w0, const float* __restrict__ w1,
                          const float* __restrict__ w2, const float* __restrict__ w3,
                          const float* __restrict__ w4, const float* __restrict__ w5,
                          const float* __restrict__ w6, short* __restrict__ wfrag) {
    int b = blockIdx.x;
    if (b < EDGE_BLOCKS) {
        int e = b * 256 + threadIdx.x;   // exact
        int d = dst[e];
        col[rowptr[d] + rank[e]] = (ushort_t)src[e];   // no atomics
    } else if (b < EDGE_BLOCKS + XSPLIT_BLOCKS) {
        int idx = (b - EDGE_BLOCKS) * 256 + threadIdx.x;   // float4 index, exact
        float4 v = ((const float4*)x)[idx];
        ushort4 o;
        o.x = bf16rne(v.x); o.y = bf16rne(v.y); o.z = bf16rne(v.z); o.w = bf16rne(v.w);
        ((ushort4*)xh)[idx] = o;
    } else {
        int tid = (b - EDGE_BLOCKS - XSPLIT_BLOCKS) * 256 + threadIdx.x;  // 0..7*4096-1
        int m = tid >> 12, t = tid & 4095;
        const float* W = (m == 0) ? w0 : (m == 1) ? w1 : (m == 2) ? w2 : (m == 3) ? w3
                       : (m == 4) ? w4 : (m == 5) ? w5 : w6;
        int j = t & 7, lane = (t >> 3) & 63, nt = (t >> 9) & 3, kt = t >> 11;
        int k = kt * 32 + ((lane >> 4) << 3) + j;
        int o = nt * 16 + (lane & 15);
        float v = W[k * 64 + o];
        unsigned short hi = bf16rne(v);
        unsigned short lo = bf16rne(v - bf2f(hi));
        wfrag[m * 8192 + t]        = (short)hi;
        wfrag[m * 8192 + 4096 + t] = (short)lo;
    }
}

// ---- pure gather over bf16 plane: one wave per node; 8 subgroups x 8 lanes ----
__global__ __launch_bounds__(512) void gather_kernel(
    const ushort_t* __restrict__ hplane, const int* __restrict__ rowptr,
    const ushort_t* __restrict__ col,
    ushort_t* __restrict__ mh, ushort_t* __restrict__ ml) {
    int gw   = (blockIdx.x * 512 + threadIdx.x) >> 6;   // node
    int lane = threadIdx.x & 63;
    int f = lane & 7;
    int g = lane >> 3;
    if (gw >= N_NODES) return;
    int beg = rowptr[gw], end = rowptr[gw + 1];
    const uint4* h16 = (const uint4*)hplane;

    float a[8] = {0.f, 0.f, 0.f, 0.f, 0.f, 0.f, 0.f, 0.f};
    float b[8] = {0.f, 0.f, 0.f, 0.f, 0.f, 0.f, 0.f, 0.f};
    int p = beg + g;
    for (; p + 8 < end; p += 16) {
        int s0 = col[p], s1 = col[p + 8];
        uint4 v0 = h16[s0 * 8 + f];
        uint4 v1 = h16[s1 * 8 + f];
        acc8(a, v0);
        acc8(b, v1);
    }
    if (p < end) {
        uint4 v = h16[col[p] * 8 + f];
        acc8(a, v);
    }
#pragma unroll
    for (int j = 0; j < 8; ++j) {
        float v = a[j] + b[j];
        v += __shfl_xor(v, 8);
        v += __shfl_xor(v, 16);
        v += __shfl_xor(v, 32);
        a[j] = v;
    }
    if (g == 0) {
        float inv = 1.0f / fmaxf((float)(end - beg), 1.0f);
        unsigned hws[4], lws[4];
#pragma unroll
        for (int i = 0; i < 4; ++i) {
            float v0 = a[2 * i] * inv, v1 = a[2 * i + 1] * inv;
            unsigned short h0 = bf16rne(v0), h1 = bf16rne(v1);
            hws[i] = (unsigned)h0 | ((unsigned)h1 << 16);
            lws[i] = (unsigned)bf16rne(v0 - bf2f(h0)) |
                     ((unsigned)bf16rne(v1 - bf2f(h1)) << 16);
        }
        uint4 hv = {hws[0], hws[1], hws[2], hws[3]};
        uint4 lv = {lws[0], lws[1], lws[2], lws[3]};
        ((uint4*)mh)[gw * 8 + f] = hv;
        ((uint4*)ml)[gw * 8 + f] = lv;
    }
}

// ---- per-tile matmul: one wave per 16 nodes; no atomics. ----
template <int XMODE>
__global__ __launch_bounds__(64) void mm_kernel(
    const float* __restrict__ xf, const ushort_t* __restrict__ xhp,
    const ushort_t* __restrict__ mh, const ushort_t* __restrict__ ml,
    const short* __restrict__ wl, const short* __restrict__ wr, const short* __restrict__ wm,
    const float* __restrict__ blv, const float* __restrict__ bmv,
    ushort_t* __restrict__ hhout) {
    __shared__ short smh[16 * TPAD];
    __shared__ short sml[16 * TPAD];
    __shared__ short sxh[16 * TPAD];
    __shared__ short sxl[16 * TPAD];
    __shared__ short sth[16 * TPAD];
    __shared__ short stl[16 * TPAD];

    int lane = threadIdx.x;
    int f = lane & 15;
    int g = lane >> 4;
    int base = blockIdx.x * 16;

    {
        const uint4* mh16 = (const uint4*)mh;
        const uint4* ml16 = (const uint4*)ml;
#pragma unroll
        for (int i = 0; i < 2; ++i) {
            int c = i * 64 + lane;
            int r = c >> 3, cc = c & 7;
            *(uint4*)&smh[r * TPAD + cc * 8] = mh16[(base + r) * 8 + cc];
            *(uint4*)&sml[r * TPAD + cc * 8] = ml16[(base + r) * 8 + cc];
        }
    }
    if (XMODE == 1) {
        const uint4* xh16 = (const uint4*)xhp;
#pragma unroll
        for (int i = 0; i < 2; ++i) {
            int c = i * 64 + lane;
            int r = c >> 3, cc = c & 7;
            *(uint4*)&sxh[r * TPAD + cc * 8] = xh16[(base + r) * 8 + cc];
        }
    } else {
        const float4* x4 = (const float4*)xf;
#pragma unroll
        for (int i = 0; i < 4; ++i) {
            int idx = i * 64 + lane;
            int r = idx >> 4, c = idx & 15;
            float4 xv = x4[(size_t)(base + r) * 16 + c];
            unsigned short h0 = bf16rne(xv.x), h1 = bf16rne(xv.y),
                           h2 = bf16rne(xv.z), h3 = bf16rne(xv.w);
            uint2 hw, lw;
            hw.x = (unsigned)h0 | ((unsigned)h1 << 16);
            hw.y = (unsigned)h2 | ((unsigned)h3 << 16);
            lw.x = (unsigned)bf16rne(xv.x - bf2f(h0)) | ((unsigned)bf16rne(xv.y - bf2f(h1)) << 16);
            lw.y = (unsigned)bf16rne(xv.z - bf2f(h2)) | ((unsigned)bf16rne(xv.w - bf2f(h3)) << 16);
            *(uint2*)&sxh[r * TPAD + c * 4] = hw;
            *(uint2*)&sxl[r * TPAD + c * 4] = lw;
        }
    }

    short8 amh[2], aml[2], axh[2], axl[2];
#pragma unroll
    for (int kt = 0; kt < 2; ++kt) {
        int idx = f * TPAD + kt * 32 + g * 8;
        amh[kt] = *(const short8*)&smh[idx];
        aml[kt] = *(const short8*)&sml[idx];
        axh[kt] = *(const short8*)&sxh[idx];
        if (XMODE == 0) axl[kt] = *(const short8*)&sxl[idx];
    }
    const short* wlh = wl;
    const short* wll = wl + 4096;
    const short* wrh = wr;
    const short* wrl = wr + 4096;

#pragma unroll
    for (int nt = 0; nt < 4; ++nt) {
        f32x4 acc = {0.f, 0.f, 0.f, 0.f};
#pragma unroll
        for (int kt = 0; kt < 2; ++kt) {
            int fi = ((kt * 4 + nt) * 64 + lane) * 8;
            short8 blh = *(const short8*)&wlh[fi];
            short8 bll = *(const short8*)&wll[fi];
            short8 brh = *(const short8*)&wrh[fi];
            short8 brl = *(const short8*)&wrl[fi];
            acc = MFMA16(amh[kt], blh, acc);
            acc = MFMA16(aml[kt], blh, acc);
            acc = MFMA16(amh[kt], bll, acc);
            acc = MFMA16(axh[kt], brh, acc);
            if (XMODE == 0) acc = MFMA16(axl[kt], brh, acc);
            acc = MFMA16(axh[kt], brl, acc);
        }
        float bias = blv[nt * 16 + f];
#pragma unroll
        for (int r = 0; r < 4; ++r) {
            float tv = acc[r] + bias;
            unsigned short hi = bf16rne(tv);
            unsigned short lo = bf16rne(tv - bf2f(hi));
            int row = g * 4 + r;
            sth[row * TPAD + nt * 16 + f] = (short)hi;
            stl[row * TPAD + nt * 16 + f] = (short)lo;
        }
    }

    short8 ath[2], atl[2];
#pragma unroll
    for (int kt = 0; kt < 2; ++kt) {
        int idx = f * TPAD + kt * 32 + g * 8;
        ath[kt] = *(const short8*)&sth[idx];
        atl[kt] = *(const short8*)&stl[idx];
    }
    const short* wmh = wm;
    const short* wml = wm + 4096;
#pragma unroll
    for (int nt = 0; nt < 4; ++nt) {
        f32x4 acc = {0.f, 0.f, 0.f, 0.f};
#pragma unroll
        for (int kt = 0; kt < 2; ++kt) {
            int fi = ((kt * 4 + nt) * 64 + lane) * 8;
            short8 bh  = *(const short8*)&wmh[fi];
            short8 bl2 = *(const short8*)&wml[fi];
            acc = MFMA16(ath[kt], bh, acc);
            acc = MFMA16(atl[kt], bh, acc);
            acc = MFMA16(ath[kt], bl2, acc);
        }
        float bias = bmv[nt * 16 + f];
#pragma unroll
        for (int r = 0; r < 4; ++r) {
            float hv = acc[r] + bias;
            hv = hv > 0.f ? hv : 0.f;
            int row  = g * 4 + r;
            int node = base + row;
            hhout[node * D + nt * 16 + f] = bf16rne(hv);
        }
    }
}

// ---- fused segmented mean-pool + MLP over bf16 h planes ----
__global__ __launch_bounds__(256) void poolmlp_kernel(
    const ushort_t* __restrict__ h0, const ushort_t* __restrict__ h1,
    const ushort_t* __restrict__ h2, const int* __restrict__ gstart,
    const float* __restrict__ W1, const float* __restrict__ b1,
    const float* __restrict__ W2, const float* __restrict__ b2,
    float* __restrict__ out) {
    __shared__ float spart[4][3][64];
    __shared__ float sg[3 * 64];
    __shared__ float tt[64];
    int gr = blockIdx.x;
    int w = threadIdx.x >> 6, lane = threadIdx.x & 63;
    int beg = gstart[gr], end = gstart[gr + 1];
    float s0 = 0.f, s1 = 0.f, s2 = 0.f;
    for (int n = beg + w; n < end; n += 4) {
        s0 += bf2f(h0[n * 64 + lane]);
        s1 += bf2f(h1[n * 64 + lane]);
        s2 += bf2f(h2[n * 64 + lane]);
    }
    spart[w][0][lane] = s0; spart[w][1][lane] = s1; spart[w][2][lane] = s2;
    __syncthreads();
    if (w == 0) {
        float inv = 1.0f / fmaxf((float)(end - beg), 1.0f);
#pragma unroll
        for (int l = 0; l < 3; ++l)
            sg[l * 64 + lane] = (spart[0][l][lane] + spart[1][l][lane] +
                                 spart[2][l][lane] + spart[3][l][lane]) * inv;
    }
    __syncthreads();
    if (w == 0) {
        float acc = b1[lane];
#pragma unroll 8
        for (int k = 0; k < 3 * 64; ++k) acc += sg[k] * W1[k * 64 + lane];
        tt[lane] = fmaxf(acc, 0.f);
    }
    __syncthreads();
    if (w == 0 && lane < D_TARGET) {
        float acc = b2[lane];
#pragma unroll
        for (int k = 0; k < 64; ++k) acc += tt[k] * W2[k * D_TARGET + lane];
        out[gr * D_TARGET + lane] = acc;
    }
}

extern "C" void kernel_launch(void* const* d_in, const int* in_sizes, int n_in,
                              void* d_out, int out_size, void* d_ws, size_t ws_size,
                              hipStream_t stream) {
    const float* x     = (const float*)d_in[0];
    const int*   ei    = (const int*)d_in[1];
    const int*   src   = ei;
    const int*   dst   = ei + N_EDGES;
    const int*   batch = (const int*)d_in[2];

    const float* Wl[3] = {(const float*)d_in[3], (const float*)d_in[6], (const float*)d_in[9]};
    const float* bl[3] = {(const float*)d_in[4], (const float*)d_in[7], (const float*)d_in[10]};
    const float* Wr[3] = {(const float*)d_in[5], (const float*)d_in[8], (const float*)d_in[11]};
    const float* Wm = (const float*)d_in[12];
    const float* bm = (const float*)d_in[13];
    const float* W1 = (const float*)d_in[14];
    const float* b1 = (const float*)d_in[15];
    const float* W2 = (const float*)d_in[16];
    const float* b2 = (const float*)d_in[17];

    // workspace layout (4-byte words; sections 16B-aligned)
    int*      degi    = (int*)d_ws;                       // 50000
    int*      partial = degi + 50000;                     // 256
    int*      rowptr  = partial + 256;                    // 50001 -> pad 50008
    int*      rank    = rowptr + 50008;                   // 800000
    int*      gstart  = rank + 800000;                    // 513 -> pad 520
    short*    wfrag   = (short*)(gstart + 520);           // 7*8192 shorts
    ushort_t* col     = (ushort_t*)(wfrag + 7 * 8192);    // 800000 ushort
    ushort_t* xh      = col + 800000;                     // 3.2M ushort
    ushort_t* mh      = xh + (size_t)N_NODES * D;
    ushort_t* ml      = mh + (size_t)N_NODES * D;
    ushort_t* hh0     = ml + (size_t)N_NODES * D;
    ushort_t* hh1     = hh0 + (size_t)N_NODES * D;
    ushort_t* hh2     = hh1 + (size_t)N_NODES * D;

    zero_kernel<<<NB_SCAN, 256, 0, stream>>>(degi);

    k1_kernel<<<EDGE_BLOCKS + NB_SCAN, 256, 0, stream>>>(dst, batch, degi, rank, gstart);
    scan_partials<<<NB_SCAN, 256, 0, stream>>>(degi, partial);
    scan_final<<<NB_SCAN, 256, 0, stream>>>(degi, partial, rowptr);
    k4_kernel<<<EDGE_BLOCKS + XSPLIT_BLOCKS + WPREP_BLOCKS, 256, 0, stream>>>(
        src, dst, rank, rowptr, col, x, xh,
        Wl[0], Wr[0], Wl[1], Wr[1], Wl[2], Wr[2], Wm, wfrag);

    ushort_t* hplanes[4] = {xh, hh0, hh1, hh2};
    for (int l = 0; l < 3; ++l) {
        gather_kernel<<<(N_NODES * 64 + 511) / 512, 512, 0, stream>>>(
            hplanes[l], rowptr, col, mh, ml);
        if (l == 0)
            mm_kernel<0><<<N_NODES / 16, 64, 0, stream>>>(
                x, nullptr, mh, ml,
                wfrag + 0 * 8192, wfrag + 1 * 8192, wfrag + 6 * 8192,
                bl[0], bm, hh0);
        else
            mm_kernel<1><<<N_NODES / 16, 64, 0, stream>>>(
                nullptr, hplanes[l], mh, ml,
                wfrag + (2 * l) * 8192, wfrag + (2 * l + 1) * 8192, wfrag + 6 * 8192,
                bl[l], bm, hplanes[l + 1]);
    }

    poolmlp_kernel<<<N_GRAPHS, 256, 0, stream>>>(hh0, hh1, hh2, gstart, W1, b1, W2, b2,
                                                 (float*)d_out);
}